// Round 9
// baseline (186.053 us; speedup 1.0000x reference)
//
#include <hip/hip_runtime.h>
#include <hip/hip_bf16.h>

#define N_NODES 100000
#define N_EDGES 1200000
#define D_IN 256
#define D_OUT 64
#define N_TILES (N_NODES / 16)                     // 6250 row tiles of 16

// fused kernel striping: period 5 = 2 GEMM blocks + 3 edge blocks
#define TILES_PER_BLOCK 8                          // 4 waves x 2 tiles
#define GEMM_NB ((N_TILES + TILES_PER_BLOCK - 1) / TILES_PER_BLOCK) // 782
#define EDGE4_NB ((N_EDGES / 4 + 255) / 256)       // 1172 (4 edges/thread)
#define STRIPE_P ((GEMM_NB + 1) / 2)               // 391 periods
#define FUSED_NB (STRIPE_P * 5)                    // 1955

#define FILL_PASSES 2
#define PASS_NODES (N_NODES / FILL_PASSES)         // 50000
#define FILL_NB EDGE4_NB

#define SCAN_BLOCK 1024
#define SCAN_NB ((N_NODES + SCAN_BLOCK - 1) / SCAN_BLOCK) // 98

typedef __bf16 bf16_t;
typedef bf16_t bf16x8 __attribute__((ext_vector_type(8)));
typedef float f32x4 __attribute__((ext_vector_type(4)));

// pack (col, val) into 4B: col<<15 | round(val*32767). val in [0,1).
__device__ __forceinline__ unsigned pack_cv(int col, float val) {
    return ((unsigned)col << 15) | (unsigned)(val * 32767.f + 0.5f);
}

__device__ __forceinline__ bf16x8 cvt8(float4 lo, float4 hi) {
    bf16x8 a;
    a[0] = (bf16_t)lo.x; a[1] = (bf16_t)lo.y;
    a[2] = (bf16_t)lo.z; a[3] = (bf16_t)lo.w;
    a[4] = (bf16_t)hi.x; a[5] = (bf16_t)hi.y;
    a[6] = (bf16_t)hi.z; a[7] = (bf16_t)hi.w;
    return a;
}

// ---------------------------------------------------------------------------
// Kernel 1: pack W[256][64] (fp32) into MFMA B-fragment order, bf16.
// ---------------------------------------------------------------------------
__global__ __launch_bounds__(256) void pack_w(const float* __restrict__ W,
                                              bf16_t* __restrict__ Wpack) {
    int id = blockIdx.x * 256 + threadIdx.x;
    if (id < D_IN * D_OUT) {
        int i  = id & 7;
        int l  = (id >> 3) & 63;
        int n  = (id >> 9) & 3;
        int kk = id >> 11;
        int k = kk * 32 + (l >> 4) * 8 + i;
        int c = n * 16 + (l & 15);
        Wpack[id] = (bf16_t)W[k * D_OUT + c];
    }
}

// ---------------------------------------------------------------------------
// Kernel 2 (fused, striped): period-5 block roles -> 2 GEMM : 3 edge.
// GEMM role: 2 tiles/wave interleaved per kk; distance-2 rotating register
// prefetch; W fragments in LDS (32 KB only -> 4+ blocks/CU); direct stores
// (already full-line coalesced, verified via WRITE_SIZE constancy R6==R8);
// s_setprio around the MFMA cluster (independent waves, attn-like case).
// Edge role: histogram + cv pack, co-resident with GEMM.
// ---------------------------------------------------------------------------
__global__ __launch_bounds__(256, 4) void gemm_hist_cv(
        const float* __restrict__ x, const bf16x8* __restrict__ Wpack,
        bf16_t* __restrict__ support,
        const int* __restrict__ erow, const int* __restrict__ ecol,
        const float* __restrict__ eval,
        int* __restrict__ counts, unsigned* __restrict__ cv) {
    __shared__ bf16x8 Wlds[2048];                  // 32 KB
    int p = blockIdx.x / 5;
    int r = blockIdx.x % 5;
    if (r < 2) {
        // ---------------- GEMM role ----------------
        int gb = p * 2 + r;                        // 0..781
        {
            int t = threadIdx.x;
#pragma unroll
            for (int i = 0; i < 8; ++i)
                Wlds[t + i * 256] = Wpack[t + i * 256];
        }
        __syncthreads();

        int wave = threadIdx.x >> 6;
        int lane = threadIdx.x & 63;
        int lrow = lane & 15;
        int g    = lane >> 4;
        int tileA = gb * TILES_PER_BLOCK + wave * 2;
        int tileB = tileA + 1;
        bool vA = (tileA < N_TILES);
        bool vB = (tileB < N_TILES);
        int tA = vA ? tileA : 0;
        int tB = vB ? tileB : 0;

        const float* __restrict__ xpA = x + (size_t)(tA * 16 + lrow) * D_IN + g * 8;
        const float* __restrict__ xpB = x + (size_t)(tB * 16 + lrow) * D_IN + g * 8;

        f32x4 a0 = {0.f,0.f,0.f,0.f}, a1 = a0, a2 = a0, a3 = a0;
        f32x4 b0 = a0, b1 = a0, b2 = a0, b3 = a0;

        // rotating 2-slot register prefetch, distance 2 over kk
        float4 sA0[2], sA1[2], sB0[2], sB1[2];
        sA0[0] = *(const float4*)(xpA +  0);
        sA1[0] = *(const float4*)(xpA +  4);
        sB0[0] = *(const float4*)(xpB +  0);
        sB1[0] = *(const float4*)(xpB +  4);
        sA0[1] = *(const float4*)(xpA + 32);
        sA1[1] = *(const float4*)(xpA + 36);
        sB0[1] = *(const float4*)(xpB + 32);
        sB1[1] = *(const float4*)(xpB + 36);

#pragma unroll
        for (int kk = 0; kk < 8; ++kk) {
            const int s = kk & 1;
            bf16x8 aA = cvt8(sA0[s], sA1[s]);
            bf16x8 aB = cvt8(sB0[s], sB1[s]);
            if (kk < 6) {   // prefetch kk+2 into freed slot, before MFMAs
                sA0[s] = *(const float4*)(xpA + (kk + 2) * 32);
                sA1[s] = *(const float4*)(xpA + (kk + 2) * 32 + 4);
                sB0[s] = *(const float4*)(xpB + (kk + 2) * 32);
                sB1[s] = *(const float4*)(xpB + (kk + 2) * 32 + 4);
            }
            bf16x8 w0 = Wlds[(kk * 4 + 0) * 64 + lane];
            bf16x8 w1 = Wlds[(kk * 4 + 1) * 64 + lane];
            bf16x8 w2 = Wlds[(kk * 4 + 2) * 64 + lane];
            bf16x8 w3 = Wlds[(kk * 4 + 3) * 64 + lane];

            __builtin_amdgcn_s_setprio(1);
            a0 = __builtin_amdgcn_mfma_f32_16x16x32_bf16(aA, w0, a0, 0, 0, 0);
            a1 = __builtin_amdgcn_mfma_f32_16x16x32_bf16(aA, w1, a1, 0, 0, 0);
            a2 = __builtin_amdgcn_mfma_f32_16x16x32_bf16(aA, w2, a2, 0, 0, 0);
            a3 = __builtin_amdgcn_mfma_f32_16x16x32_bf16(aA, w3, a3, 0, 0, 0);
            b0 = __builtin_amdgcn_mfma_f32_16x16x32_bf16(aB, w0, b0, 0, 0, 0);
            b1 = __builtin_amdgcn_mfma_f32_16x16x32_bf16(aB, w1, b1, 0, 0, 0);
            b2 = __builtin_amdgcn_mfma_f32_16x16x32_bf16(aB, w2, b2, 0, 0, 0);
            b3 = __builtin_amdgcn_mfma_f32_16x16x32_bf16(aB, w3, b3, 0, 0, 0);
            __builtin_amdgcn_s_setprio(0);
        }

        if (vA) {
            bf16_t* __restrict__ sp = support + (size_t)tA * 16 * D_OUT;
#pragma unroll
            for (int q = 0; q < 4; ++q) {
                int row = g * 4 + q;
                sp[row * D_OUT +  0 + lrow] = (bf16_t)a0[q];
                sp[row * D_OUT + 16 + lrow] = (bf16_t)a1[q];
                sp[row * D_OUT + 32 + lrow] = (bf16_t)a2[q];
                sp[row * D_OUT + 48 + lrow] = (bf16_t)a3[q];
            }
        }
        if (vB) {
            bf16_t* __restrict__ sp = support + (size_t)tB * 16 * D_OUT;
#pragma unroll
            for (int q = 0; q < 4; ++q) {
                int row = g * 4 + q;
                sp[row * D_OUT +  0 + lrow] = (bf16_t)b0[q];
                sp[row * D_OUT + 16 + lrow] = (bf16_t)b1[q];
                sp[row * D_OUT + 32 + lrow] = (bf16_t)b2[q];
                sp[row * D_OUT + 48 + lrow] = (bf16_t)b3[q];
            }
        }
    } else {
        // ---------------- edge role: histogram + cv pack ----------------
        int eb = p * 3 + (r - 2);                  // 0..1171
        if (eb >= EDGE4_NB) return;
        int e = (eb * 256 + threadIdx.x) * 4;
        if (e + 3 < N_EDGES) {
            int4   r4 = *(const int4*)(erow + e);
            int4   c4 = *(const int4*)(ecol + e);
            float4 v4 = *(const float4*)(eval + e);
            atomicAdd(&counts[r4.x], 1);
            atomicAdd(&counts[r4.y], 1);
            atomicAdd(&counts[r4.z], 1);
            atomicAdd(&counts[r4.w], 1);
            uint4 o;
            o.x = pack_cv(c4.x, v4.x);
            o.y = pack_cv(c4.y, v4.y);
            o.z = pack_cv(c4.z, v4.z);
            o.w = pack_cv(c4.w, v4.w);
            *(uint4*)(cv + e) = o;
        } else {
            for (int i = 0; i < 4; ++i) {
                if (e + i < N_EDGES) {
                    atomicAdd(&counts[erow[e + i]], 1);
                    cv[e + i] = pack_cv(ecol[e + i], eval[e + i]);
                }
            }
        }
    }
}

// ---------------------------------------------------------------------------
// Kernel 3a: per-block partial sums of counts (1024 counts per block).
// ---------------------------------------------------------------------------
__global__ __launch_bounds__(256) void partial_k(const int* __restrict__ counts,
                                                 int* __restrict__ bsum) {
    int b = blockIdx.x, t = threadIdx.x;
    int base = b * SCAN_BLOCK + t * 4;
    int s = 0;
    if (base + 3 < N_NODES) {
        int4 v = *(const int4*)(counts + base);
        s = v.x + v.y + v.z + v.w;
    } else {
#pragma unroll
        for (int i = 0; i < 4; ++i)
            if (base + i < N_NODES) s += counts[base + i];
    }
#pragma unroll
    for (int off = 32; off > 0; off >>= 1) s += __shfl_down(s, off);
    __shared__ int sh[4];
    if ((t & 63) == 0) sh[t >> 6] = s;
    __syncthreads();
    if (t == 0) bsum[b] = sh[0] + sh[1] + sh[2] + sh[3];
}

// ---------------------------------------------------------------------------
// Kernel 3b: scan the 98 block sums (1 tiny block). Also writes offsets[N].
// ---------------------------------------------------------------------------
__global__ __launch_bounds__(128) void scan_bsum_k(const int* __restrict__ bsum,
                                                   int* __restrict__ bpre,
                                                   int* __restrict__ offsets) {
    __shared__ int sh[128];
    int t = threadIdx.x;
    int v = (t < SCAN_NB) ? bsum[t] : 0;
    sh[t] = v;
    __syncthreads();
    for (int off = 1; off < 128; off <<= 1) {
        int add = (t >= off) ? sh[t - off] : 0;
        __syncthreads();
        sh[t] += add;
        __syncthreads();
    }
    if (t < SCAN_NB) bpre[t] = sh[t] - v;
    if (t == 127) offsets[N_NODES] = sh[127];
}

// ---------------------------------------------------------------------------
// Kernel 3c: block-local scan + global prefix -> offsets, cursor.
// ---------------------------------------------------------------------------
__global__ __launch_bounds__(256) void emit_k(const int* __restrict__ counts,
                                              const int* __restrict__ bpre,
                                              int* __restrict__ offsets,
                                              int* __restrict__ cursor) {
    __shared__ int sh[256];
    int b = blockIdx.x, t = threadIdx.x;
    int base = b * SCAN_BLOCK + t * 4;
    int c0 = 0, c1 = 0, c2 = 0, c3 = 0;
    if (base + 3 < N_NODES) {
        int4 v = *(const int4*)(counts + base);
        c0 = v.x; c1 = v.y; c2 = v.z; c3 = v.w;
    } else {
        if (base + 0 < N_NODES) c0 = counts[base + 0];
        if (base + 1 < N_NODES) c1 = counts[base + 1];
        if (base + 2 < N_NODES) c2 = counts[base + 2];
        if (base + 3 < N_NODES) c3 = counts[base + 3];
    }
    int sum4 = c0 + c1 + c2 + c3;
    sh[t] = sum4;
    __syncthreads();
    for (int off = 1; off < 256; off <<= 1) {
        int add = (t >= off) ? sh[t - off] : 0;
        __syncthreads();
        sh[t] += add;
        __syncthreads();
    }
    int run = bpre[b] + sh[t] - sum4;
    if (base + 0 < N_NODES) { offsets[base + 0] = run; cursor[base + 0] = run; run += c0; }
    if (base + 1 < N_NODES) { offsets[base + 1] = run; cursor[base + 1] = run; run += c1; }
    if (base + 2 < N_NODES) { offsets[base + 2] = run; cursor[base + 2] = run; run += c2; }
    if (base + 3 < N_NODES) { offsets[base + 3] = run; cursor[base + 3] = run; run += c3; }
}

// ---------------------------------------------------------------------------
// Kernel 4: predicated CSR fill, one pass per row range [lo, hi).
// ---------------------------------------------------------------------------
__global__ __launch_bounds__(256) void fill_k(const int* __restrict__ erow,
                                              const unsigned* __restrict__ cv,
                                              int* __restrict__ cursor,
                                              unsigned* __restrict__ csr,
                                              int lo, int hi) {
    int t = blockIdx.x * 256 + threadIdx.x;
    int e = t * 4;
    if (e + 3 < N_EDGES) {
        int4  r4 = *(const int4*)(erow + e);
        uint4 c4 = *(const uint4*)(cv + e);
        if (r4.x >= lo && r4.x < hi) { int q = atomicAdd(&cursor[r4.x], 1); csr[q] = c4.x; }
        if (r4.y >= lo && r4.y < hi) { int q = atomicAdd(&cursor[r4.y], 1); csr[q] = c4.y; }
        if (r4.z >= lo && r4.z < hi) { int q = atomicAdd(&cursor[r4.z], 1); csr[q] = c4.z; }
        if (r4.w >= lo && r4.w < hi) { int q = atomicAdd(&cursor[r4.w], 1); csr[q] = c4.w; }
    } else {
        for (int i = 0; i < 4; ++i) {
            if (e + i < N_EDGES) {
                int rr = erow[e + i];
                if (rr >= lo && rr < hi) {
                    int q = atomicAdd(&cursor[rr], 1);
                    csr[q] = cv[e + i];
                }
            }
        }
    }
}

// ---------------------------------------------------------------------------
// Kernel 5: aggregate + ReLU. One wave per node, lane = feature.
// 8-deep ILP: 8 independent csr loads then 8 independent support gathers.
// ---------------------------------------------------------------------------
__global__ __launch_bounds__(256) void agg_k(const int* __restrict__ offsets,
                                             const unsigned* __restrict__ csr,
                                             const bf16_t* __restrict__ support,
                                             float* __restrict__ out) {
    int node = blockIdx.x * 4 + (threadIdx.x >> 6);
    int lane = threadIdx.x & 63;
    if (node >= N_NODES) return;
    int s = offsets[node];
    int e = offsets[node + 1];
    const float inv = 1.f / 32767.f;
    float acc = 0.f;
    int p = s;
    for (; p + 8 <= e; p += 8) {
        unsigned w0 = csr[p + 0], w1 = csr[p + 1], w2 = csr[p + 2], w3 = csr[p + 3];
        unsigned w4 = csr[p + 4], w5 = csr[p + 5], w6 = csr[p + 6], w7 = csr[p + 7];
        float s0 = (float)support[(size_t)(w0 >> 15) * D_OUT + lane];
        float s1 = (float)support[(size_t)(w1 >> 15) * D_OUT + lane];
        float s2 = (float)support[(size_t)(w2 >> 15) * D_OUT + lane];
        float s3 = (float)support[(size_t)(w3 >> 15) * D_OUT + lane];
        float s4 = (float)support[(size_t)(w4 >> 15) * D_OUT + lane];
        float s5 = (float)support[(size_t)(w5 >> 15) * D_OUT + lane];
        float s6 = (float)support[(size_t)(w6 >> 15) * D_OUT + lane];
        float s7 = (float)support[(size_t)(w7 >> 15) * D_OUT + lane];
        acc = fmaf((float)(w0 & 0x7fffu) * inv, s0, acc);
        acc = fmaf((float)(w1 & 0x7fffu) * inv, s1, acc);
        acc = fmaf((float)(w2 & 0x7fffu) * inv, s2, acc);
        acc = fmaf((float)(w3 & 0x7fffu) * inv, s3, acc);
        acc = fmaf((float)(w4 & 0x7fffu) * inv, s4, acc);
        acc = fmaf((float)(w5 & 0x7fffu) * inv, s5, acc);
        acc = fmaf((float)(w6 & 0x7fffu) * inv, s6, acc);
        acc = fmaf((float)(w7 & 0x7fffu) * inv, s7, acc);
    }
    for (; p + 4 <= e; p += 4) {
        unsigned w0 = csr[p + 0], w1 = csr[p + 1], w2 = csr[p + 2], w3 = csr[p + 3];
        float s0 = (float)support[(size_t)(w0 >> 15) * D_OUT + lane];
        float s1 = (float)support[(size_t)(w1 >> 15) * D_OUT + lane];
        float s2 = (float)support[(size_t)(w2 >> 15) * D_OUT + lane];
        float s3 = (float)support[(size_t)(w3 >> 15) * D_OUT + lane];
        acc = fmaf((float)(w0 & 0x7fffu) * inv, s0, acc);
        acc = fmaf((float)(w1 & 0x7fffu) * inv, s1, acc);
        acc = fmaf((float)(w2 & 0x7fffu) * inv, s2, acc);
        acc = fmaf((float)(w3 & 0x7fffu) * inv, s3, acc);
    }
    for (; p < e; ++p) {
        unsigned w = csr[p];
        acc = fmaf((float)(w & 0x7fffu) * inv,
                   (float)support[(size_t)(w >> 15) * D_OUT + lane], acc);
    }
    out[(size_t)node * D_OUT + lane] = fmaxf(acc, 0.f);
}

extern "C" void kernel_launch(void* const* d_in, const int* in_sizes, int n_in,
                              void* d_out, int out_size, void* d_ws, size_t ws_size,
                              hipStream_t stream) {
    const float* x    = (const float*)d_in[0];
    const int*   erow = (const int*)d_in[1];
    const int*   ecol = (const int*)d_in[2];
    const float* eval = (const float*)d_in[3];
    const float* W    = (const float*)d_in[4];
    float* out = (float*)d_out;

    // ---- workspace layout (16B-aligned segments, ~23.6 MB) ----
    char* ws = (char*)d_ws;
    bf16_t*   support = (bf16_t*)ws;                         // 12,800,000
    bf16_t*   WpackS  = (bf16_t*)(ws + 12800000);            //     32,768
    int*      counts  = (int*)(ws + 12832768);               //    400,000
    int*      offsets = (int*)(ws + 13232768);               //    400,004
    int*      cursor  = (int*)(ws + 13632896);               //    400,000
    unsigned* cv      = (unsigned*)(ws + 14032896);          //  4,800,000
    unsigned* csr     = (unsigned*)(ws + 18832896);          //  4,800,000
    int*      bsum    = (int*)(ws + 23632896);               //        392
    int*      bpre    = (int*)(ws + 23633288);               //        392

    // 1) pack W into bf16 MFMA B-fragments
    pack_w<<<(D_IN * D_OUT + 255) / 256, 256, 0, stream>>>(W, WpackS);

    // 2) zero counts, then fused (striped) GEMM + histogram + cv pack
    hipMemsetAsync(counts, 0, (size_t)N_NODES * sizeof(int), stream);
    gemm_hist_cv<<<FUSED_NB, 256, 0, stream>>>(
        x, (const bf16x8*)WpackS, support, erow, ecol, eval, counts, cv);

    // 3) hierarchical scan -> offsets, cursor
    partial_k<<<SCAN_NB, 256, 0, stream>>>(counts, bsum);
    scan_bsum_k<<<1, 128, 0, stream>>>(bsum, bpre, offsets);
    emit_k<<<SCAN_NB, 256, 0, stream>>>(counts, bpre, offsets, cursor);

    // 4) predicated CSR fill, 2 L2-localized passes
    for (int p = 0; p < FILL_PASSES; ++p) {
        fill_k<<<FILL_NB, 256, 0, stream>>>(erow, cv, cursor, csr,
                                            p * PASS_NODES, (p + 1) * PASS_NODES);
    }

    // 5) aggregate + ReLU (no atomics, writes every output element)
    agg_k<<<(N_NODES + 3) / 4, 256, 0, stream>>>(offsets, csr, support, out);
}

// Round 10
// 176.610 us; speedup vs baseline: 1.0535x; 1.0535x over previous
//
#include <hip/hip_runtime.h>
#include <hip/hip_bf16.h>

#define N_NODES 100000
#define N_EDGES 1200000
#define D_IN 256
#define D_OUT 64
#define N_TILES (N_NODES / 16)                     // 6250 row tiles of 16

#define NG 1280                                    // GEMM blocks (5/CU x 256)
#define FUSED_NB (NG * 2)                          // even bid: GEMM, odd: edge
#define EDGE4_NB ((N_EDGES / 4 + 255) / 256)       // 1172 (4 edges/thread)

#define FILL_PASSES 2
#define PASS_NODES (N_NODES / FILL_PASSES)         // 50000
#define FILL_NB EDGE4_NB

#define SCAN_BLOCK 1024
#define SCAN_NB ((N_NODES + SCAN_BLOCK - 1) / SCAN_BLOCK) // 98

typedef __bf16 bf16_t;
typedef bf16_t bf16x8 __attribute__((ext_vector_type(8)));
typedef float f32x4 __attribute__((ext_vector_type(4)));

// pack (col, val) into 4B: col<<15 | round(val*32767). val in [0,1).
__device__ __forceinline__ unsigned pack_cv(int col, float val) {
    return ((unsigned)col << 15) | (unsigned)(val * 32767.f + 0.5f);
}

__device__ __forceinline__ bf16x8 cvt8(float4 lo, float4 hi) {
    bf16x8 a;
    a[0] = (bf16_t)lo.x; a[1] = (bf16_t)lo.y;
    a[2] = (bf16_t)lo.z; a[3] = (bf16_t)lo.w;
    a[4] = (bf16_t)hi.x; a[5] = (bf16_t)hi.y;
    a[6] = (bf16_t)hi.z; a[7] = (bf16_t)hi.w;
    return a;
}

// async global->LDS, 16B per lane, dest = wave-uniform base + lane*16
__device__ __forceinline__ void gld_lds16(const void* g, void* l) {
    __builtin_amdgcn_global_load_lds(
        (const __attribute__((address_space(1))) void*)g,
        (__attribute__((address_space(3))) void*)l, 16, 0, 0);
}

// ---------------------------------------------------------------------------
// Kernel 1: pack W[256][64] (fp32) into MFMA B-fragment order, bf16.
// ---------------------------------------------------------------------------
__global__ __launch_bounds__(256) void pack_w(const float* __restrict__ W,
                                              bf16_t* __restrict__ Wpack) {
    int id = blockIdx.x * 256 + threadIdx.x;
    if (id < D_IN * D_OUT) {
        int i  = id & 7;
        int l  = (id >> 3) & 63;
        int n  = (id >> 9) & 3;
        int kk = id >> 11;
        int k = kk * 32 + (l >> 4) * 8 + i;
        int c = n * 16 + (l & 15);
        Wpack[id] = (bf16_t)W[k * D_OUT + c];
    }
}

// Stage one x tile (16 rows x 256 f32 = 16KB, contiguous in global) into LDS
// laid out [kk][half][lane]x16B so reads are lane*16-contiguous (conflict-free).
// 4 global_load_lds issues per thread; LDS dest base wave-uniform; global src
// per-lane permuted to match the layout.
__device__ __forceinline__ void stage_tile(const char* __restrict__ xtile,
                                           char* ldsbuf, int wave, int lane) {
#pragma unroll
    for (int i = 0; i < 4; ++i) {
        int kk = i * 2 + (wave >> 1);
        const char* src = xtile + (lane & 15) * 1024 + (lane >> 4) * 32
                        + kk * 128 + (wave & 1) * 16;
        gld_lds16(src, ldsbuf + i * 4096 + wave * 1024);
    }
}

// Compute one tile from LDS and store its 16x16 output sub-tile (cols
// wave*16..wave*16+15). W fragments live in registers (wf[kk]).
__device__ __forceinline__ void compute_store(const char* buf,
                                              const bf16x8* wf,
                                              int lane, int lrow, int g, int wave,
                                              bf16_t* __restrict__ support,
                                              int tile) {
    f32x4 acc = {0.f, 0.f, 0.f, 0.f};
#pragma unroll
    for (int kk = 0; kk < 8; ++kk) {
        float4 lo = *(const float4*)(buf + kk * 2048 + lane * 16);
        float4 hi = *(const float4*)(buf + kk * 2048 + 1024 + lane * 16);
        acc = __builtin_amdgcn_mfma_f32_16x16x32_bf16(cvt8(lo, hi), wf[kk],
                                                      acc, 0, 0, 0);
    }
    bf16_t* __restrict__ sp = support + (size_t)tile * 16 * D_OUT
                            + wave * 16 + lrow;
#pragma unroll
    for (int q = 0; q < 4; ++q)
        sp[(g * 4 + q) * D_OUT] = (bf16_t)acc[q];
}

// ---------------------------------------------------------------------------
// Kernel 2 (fused): even blocks = GEMM (grid-stride over row tiles, x staged
// via double-buffered global_load_lds, counted vmcnt(4), raw barriers);
// odd blocks = edge histogram + cv pack, co-resident with GEMM.
// ---------------------------------------------------------------------------
__global__ __launch_bounds__(256, 5) void gemm_hist_cv(
        const float* __restrict__ x, const bf16x8* __restrict__ Wpack,
        bf16_t* __restrict__ support,
        const int* __restrict__ erow, const int* __restrict__ ecol,
        const float* __restrict__ eval,
        int* __restrict__ counts, unsigned* __restrict__ cv) {
    __shared__ char xlds[2][16384];                // 32 KB double buffer
    int bid  = blockIdx.x;
    int role = bid & 1;
    int idx  = bid >> 1;
    if (role == 0) {
        // ---------------- GEMM role ----------------
        int lane = threadIdx.x & 63;
        int wave = threadIdx.x >> 6;
        int lrow = lane & 15;
        int g    = lane >> 4;

        // W fragments for this wave's 16-col tile: 8 x bf16x8 = 32 VGPRs
        bf16x8 wf[8];
#pragma unroll
        for (int kk = 0; kk < 8; ++kk)
            wf[kk] = Wpack[(kk * 4 + wave) * 64 + lane];

        const char* xc = (const char*)x;
        int t = idx;                               // idx in [0, NG)
        stage_tile(xc + (size_t)t * 16384, xlds[0], wave, lane);
        int cur = 0;
#pragma unroll 1
        for (; t < N_TILES; t += NG) {
            int nxt = t + NG;
            if (nxt < N_TILES) {
                stage_tile(xc + (size_t)nxt * 16384, xlds[cur ^ 1], wave, lane);
                asm volatile("s_waitcnt vmcnt(4)" ::: "memory");
            } else {
                asm volatile("s_waitcnt vmcnt(0)" ::: "memory");
            }
            __builtin_amdgcn_s_barrier();          // staged data visible
            __builtin_amdgcn_sched_barrier(0);     // pin ds_reads below
            compute_store(xlds[cur], wf, lane, lrow, g, wave, support, t);
            __builtin_amdgcn_s_barrier();          // all waves done reading
            __builtin_amdgcn_sched_barrier(0);     // pin next stage below
            cur ^= 1;
        }
    } else {
        // ---------------- edge role: histogram + cv pack ----------------
        if (idx >= EDGE4_NB) return;
        int e = (idx * 256 + threadIdx.x) * 4;
        if (e + 3 < N_EDGES) {
            int4   r4 = *(const int4*)(erow + e);
            int4   c4 = *(const int4*)(ecol + e);
            float4 v4 = *(const float4*)(eval + e);
            atomicAdd(&counts[r4.x], 1);
            atomicAdd(&counts[r4.y], 1);
            atomicAdd(&counts[r4.z], 1);
            atomicAdd(&counts[r4.w], 1);
            uint4 o;
            o.x = pack_cv(c4.x, v4.x);
            o.y = pack_cv(c4.y, v4.y);
            o.z = pack_cv(c4.z, v4.z);
            o.w = pack_cv(c4.w, v4.w);
            *(uint4*)(cv + e) = o;
        } else {
            for (int i = 0; i < 4; ++i) {
                if (e + i < N_EDGES) {
                    atomicAdd(&counts[erow[e + i]], 1);
                    cv[e + i] = pack_cv(ecol[e + i], eval[e + i]);
                }
            }
        }
    }
}

// ---------------------------------------------------------------------------
// Kernel 3a: per-block partial sums of counts (1024 counts per block).
// ---------------------------------------------------------------------------
__global__ __launch_bounds__(256) void partial_k(const int* __restrict__ counts,
                                                 int* __restrict__ bsum) {
    int b = blockIdx.x, t = threadIdx.x;
    int base = b * SCAN_BLOCK + t * 4;
    int s = 0;
    if (base + 3 < N_NODES) {
        int4 v = *(const int4*)(counts + base);
        s = v.x + v.y + v.z + v.w;
    } else {
#pragma unroll
        for (int i = 0; i < 4; ++i)
            if (base + i < N_NODES) s += counts[base + i];
    }
#pragma unroll
    for (int off = 32; off > 0; off >>= 1) s += __shfl_down(s, off);
    __shared__ int sh[4];
    if ((t & 63) == 0) sh[t >> 6] = s;
    __syncthreads();
    if (t == 0) bsum[b] = sh[0] + sh[1] + sh[2] + sh[3];
}

// ---------------------------------------------------------------------------
// Kernel 3b: scan the 98 block sums (1 tiny block). Also writes offsets[N].
// ---------------------------------------------------------------------------
__global__ __launch_bounds__(128) void scan_bsum_k(const int* __restrict__ bsum,
                                                   int* __restrict__ bpre,
                                                   int* __restrict__ offsets) {
    __shared__ int sh[128];
    int t = threadIdx.x;
    int v = (t < SCAN_NB) ? bsum[t] : 0;
    sh[t] = v;
    __syncthreads();
    for (int off = 1; off < 128; off <<= 1) {
        int add = (t >= off) ? sh[t - off] : 0;
        __syncthreads();
        sh[t] += add;
        __syncthreads();
    }
    if (t < SCAN_NB) bpre[t] = sh[t] - v;
    if (t == 127) offsets[N_NODES] = sh[127];
}

// ---------------------------------------------------------------------------
// Kernel 3c: block-local scan + global prefix -> offsets, cursor.
// ---------------------------------------------------------------------------
__global__ __launch_bounds__(256) void emit_k(const int* __restrict__ counts,
                                              const int* __restrict__ bpre,
                                              int* __restrict__ offsets,
                                              int* __restrict__ cursor) {
    __shared__ int sh[256];
    int b = blockIdx.x, t = threadIdx.x;
    int base = b * SCAN_BLOCK + t * 4;
    int c0 = 0, c1 = 0, c2 = 0, c3 = 0;
    if (base + 3 < N_NODES) {
        int4 v = *(const int4*)(counts + base);
        c0 = v.x; c1 = v.y; c2 = v.z; c3 = v.w;
    } else {
        if (base + 0 < N_NODES) c0 = counts[base + 0];
        if (base + 1 < N_NODES) c1 = counts[base + 1];
        if (base + 2 < N_NODES) c2 = counts[base + 2];
        if (base + 3 < N_NODES) c3 = counts[base + 3];
    }
    int sum4 = c0 + c1 + c2 + c3;
    sh[t] = sum4;
    __syncthreads();
    for (int off = 1; off < 256; off <<= 1) {
        int add = (t >= off) ? sh[t - off] : 0;
        __syncthreads();
        sh[t] += add;
        __syncthreads();
    }
    int run = bpre[b] + sh[t] - sum4;
    if (base + 0 < N_NODES) { offsets[base + 0] = run; cursor[base + 0] = run; run += c0; }
    if (base + 1 < N_NODES) { offsets[base + 1] = run; cursor[base + 1] = run; run += c1; }
    if (base + 2 < N_NODES) { offsets[base + 2] = run; cursor[base + 2] = run; run += c2; }
    if (base + 3 < N_NODES) { offsets[base + 3] = run; cursor[base + 3] = run; run += c3; }
}

// ---------------------------------------------------------------------------
// Kernel 4: predicated CSR fill, one pass per row range [lo, hi).
// ---------------------------------------------------------------------------
__global__ __launch_bounds__(256) void fill_k(const int* __restrict__ erow,
                                              const unsigned* __restrict__ cv,
                                              int* __restrict__ cursor,
                                              unsigned* __restrict__ csr,
                                              int lo, int hi) {
    int t = blockIdx.x * 256 + threadIdx.x;
    int e = t * 4;
    if (e + 3 < N_EDGES) {
        int4  r4 = *(const int4*)(erow + e);
        uint4 c4 = *(const uint4*)(cv + e);
        if (r4.x >= lo && r4.x < hi) { int q = atomicAdd(&cursor[r4.x], 1); csr[q] = c4.x; }
        if (r4.y >= lo && r4.y < hi) { int q = atomicAdd(&cursor[r4.y], 1); csr[q] = c4.y; }
        if (r4.z >= lo && r4.z < hi) { int q = atomicAdd(&cursor[r4.z], 1); csr[q] = c4.z; }
        if (r4.w >= lo && r4.w < hi) { int q = atomicAdd(&cursor[r4.w], 1); csr[q] = c4.w; }
    } else {
        for (int i = 0; i < 4; ++i) {
            if (e + i < N_EDGES) {
                int rr = erow[e + i];
                if (rr >= lo && rr < hi) {
                    int q = atomicAdd(&cursor[rr], 1);
                    csr[q] = cv[e + i];
                }
            }
        }
    }
}

// ---------------------------------------------------------------------------
// Kernel 5: aggregate + ReLU. One wave per node, lane = feature.
// 8-deep ILP: 8 independent csr loads then 8 independent support gathers.
// ---------------------------------------------------------------------------
__global__ __launch_bounds__(256) void agg_k(const int* __restrict__ offsets,
                                             const unsigned* __restrict__ csr,
                                             const bf16_t* __restrict__ support,
                                             float* __restrict__ out) {
    int node = blockIdx.x * 4 + (threadIdx.x >> 6);
    int lane = threadIdx.x & 63;
    if (node >= N_NODES) return;
    int s = offsets[node];
    int e = offsets[node + 1];
    const float inv = 1.f / 32767.f;
    float acc = 0.f;
    int p = s;
    for (; p + 8 <= e; p += 8) {
        unsigned w0 = csr[p + 0], w1 = csr[p + 1], w2 = csr[p + 2], w3 = csr[p + 3];
        unsigned w4 = csr[p + 4], w5 = csr[p + 5], w6 = csr[p + 6], w7 = csr[p + 7];
        float s0 = (float)support[(size_t)(w0 >> 15) * D_OUT + lane];
        float s1 = (float)support[(size_t)(w1 >> 15) * D_OUT + lane];
        float s2 = (float)support[(size_t)(w2 >> 15) * D_OUT + lane];
        float s3 = (float)support[(size_t)(w3 >> 15) * D_OUT + lane];
        float s4 = (float)support[(size_t)(w4 >> 15) * D_OUT + lane];
        float s5 = (float)support[(size_t)(w5 >> 15) * D_OUT + lane];
        float s6 = (float)support[(size_t)(w6 >> 15) * D_OUT + lane];
        float s7 = (float)support[(size_t)(w7 >> 15) * D_OUT + lane];
        acc = fmaf((float)(w0 & 0x7fffu) * inv, s0, acc);
        acc = fmaf((float)(w1 & 0x7fffu) * inv, s1, acc);
        acc = fmaf((float)(w2 & 0x7fffu) * inv, s2, acc);
        acc = fmaf((float)(w3 & 0x7fffu) * inv, s3, acc);
        acc = fmaf((float)(w4 & 0x7fffu) * inv, s4, acc);
        acc = fmaf((float)(w5 & 0x7fffu) * inv, s5, acc);
        acc = fmaf((float)(w6 & 0x7fffu) * inv, s6, acc);
        acc = fmaf((float)(w7 & 0x7fffu) * inv, s7, acc);
    }
    for (; p + 4 <= e; p += 4) {
        unsigned w0 = csr[p + 0], w1 = csr[p + 1], w2 = csr[p + 2], w3 = csr[p + 3];
        float s0 = (float)support[(size_t)(w0 >> 15) * D_OUT + lane];
        float s1 = (float)support[(size_t)(w1 >> 15) * D_OUT + lane];
        float s2 = (float)support[(size_t)(w2 >> 15) * D_OUT + lane];
        float s3 = (float)support[(size_t)(w3 >> 15) * D_OUT + lane];
        acc = fmaf((float)(w0 & 0x7fffu) * inv, s0, acc);
        acc = fmaf((float)(w1 & 0x7fffu) * inv, s1, acc);
        acc = fmaf((float)(w2 & 0x7fffu) * inv, s2, acc);
        acc = fmaf((float)(w3 & 0x7fffu) * inv, s3, acc);
    }
    for (; p < e; ++p) {
        unsigned w = csr[p];
        acc = fmaf((float)(w & 0x7fffu) * inv,
                   (float)support[(size_t)(w >> 15) * D_OUT + lane], acc);
    }
    out[(size_t)node * D_OUT + lane] = fmaxf(acc, 0.f);
}

extern "C" void kernel_launch(void* const* d_in, const int* in_sizes, int n_in,
                              void* d_out, int out_size, void* d_ws, size_t ws_size,
                              hipStream_t stream) {
    const float* x    = (const float*)d_in[0];
    const int*   erow = (const int*)d_in[1];
    const int*   ecol = (const int*)d_in[2];
    const float* eval = (const float*)d_in[3];
    const float* W    = (const float*)d_in[4];
    float* out = (float*)d_out;

    // ---- workspace layout (16B-aligned segments, ~23.6 MB) ----
    char* ws = (char*)d_ws;
    bf16_t*   support = (bf16_t*)ws;                         // 12,800,000
    bf16_t*   WpackS  = (bf16_t*)(ws + 12800000);            //     32,768
    int*      counts  = (int*)(ws + 12832768);               //    400,000
    int*      offsets = (int*)(ws + 13232768);               //    400,004
    int*      cursor  = (int*)(ws + 13632896);               //    400,000
    unsigned* cv      = (unsigned*)(ws + 14032896);          //  4,800,000
    unsigned* csr     = (unsigned*)(ws + 18832896);          //  4,800,000
    int*      bsum    = (int*)(ws + 23632896);               //        392
    int*      bpre    = (int*)(ws + 23633288);               //        392

    // 1) pack W into bf16 MFMA B-fragments
    pack_w<<<(D_IN * D_OUT + 255) / 256, 256, 0, stream>>>(W, WpackS);

    // 2) zero counts, then fused GEMM (global_load_lds pipeline) + hist + cv
    hipMemsetAsync(counts, 0, (size_t)N_NODES * sizeof(int), stream);
    gemm_hist_cv<<<FUSED_NB, 256, 0, stream>>>(
        x, (const bf16x8*)WpackS, support, erow, ecol, eval, counts, cv);

    // 3) hierarchical scan -> offsets, cursor
    partial_k<<<SCAN_NB, 256, 0, stream>>>(counts, bsum);
    scan_bsum_k<<<1, 128, 0, stream>>>(bsum, bpre, offsets);
    emit_k<<<SCAN_NB, 256, 0, stream>>>(counts, bpre, offsets, cursor);

    // 4) predicated CSR fill, 2 L2-localized passes
    for (int p = 0; p < FILL_PASSES; ++p) {
        fill_k<<<FILL_NB, 256, 0, stream>>>(erow, cv, cursor, csr,
                                            p * PASS_NODES, (p + 1) * PASS_NODES);
    }

    // 5) aggregate + ReLU (no atomics, writes every output element)
    agg_k<<<(N_NODES + 3) / 4, 256, 0, stream>>>(offsets, csr, support, out);
}

// Round 11
// 172.065 us; speedup vs baseline: 1.0813x; 1.0264x over previous
//
#include <hip/hip_runtime.h>
#include <hip/hip_bf16.h>

#define N_NODES 100000
#define N_EDGES 1200000
#define D_IN 256
#define D_OUT 64
#define N_TILES (N_NODES / 16)                     // 6250 row tiles of 16

#define NG 1280                                    // GEMM blocks = 5/CU x 256
#define EDGE4_NB ((N_EDGES / 4 + 255) / 256)       // 1172 (4 edges/thread)

#define FILL_PASSES 2
#define PASS_NODES (N_NODES / FILL_PASSES)         // 50000
#define FILL_NB EDGE4_NB

#define SCAN_BLOCK 1024
#define SCAN_NB ((N_NODES + SCAN_BLOCK - 1) / SCAN_BLOCK) // 98

typedef __bf16 bf16_t;
typedef bf16_t bf16x8 __attribute__((ext_vector_type(8)));
typedef float f32x4 __attribute__((ext_vector_type(4)));

// pack (col, val) into 4B: col<<15 | round(val*32767). val in [0,1).
__device__ __forceinline__ unsigned pack_cv(int col, float val) {
    return ((unsigned)col << 15) | (unsigned)(val * 32767.f + 0.5f);
}

__device__ __forceinline__ bf16x8 cvt8(float4 lo, float4 hi) {
    bf16x8 a;
    a[0] = (bf16_t)lo.x; a[1] = (bf16_t)lo.y;
    a[2] = (bf16_t)lo.z; a[3] = (bf16_t)lo.w;
    a[4] = (bf16_t)hi.x; a[5] = (bf16_t)hi.y;
    a[6] = (bf16_t)hi.z; a[7] = (bf16_t)hi.w;
    return a;
}

// async global->LDS, 16B per lane, dest = wave-uniform base + lane*16
__device__ __forceinline__ void gld_lds16(const void* g, void* l) {
    __builtin_amdgcn_global_load_lds(
        (const __attribute__((address_space(1))) void*)g,
        (__attribute__((address_space(3))) void*)l, 16, 0, 0);
}

// ---------------------------------------------------------------------------
// Kernel 1: pack W[256][64] (fp32) into MFMA B-fragment order, bf16.
// ---------------------------------------------------------------------------
__global__ __launch_bounds__(256) void pack_w(const float* __restrict__ W,
                                              bf16_t* __restrict__ Wpack) {
    int id = blockIdx.x * 256 + threadIdx.x;
    if (id < D_IN * D_OUT) {
        int i  = id & 7;
        int l  = (id >> 3) & 63;
        int n  = (id >> 9) & 3;
        int kk = id >> 11;
        int k = kk * 32 + (l >> 4) * 8 + i;
        int c = n * 16 + (l & 15);
        Wpack[id] = (bf16_t)W[k * D_OUT + c];
    }
}

// Stage one x tile (16 rows x 256 f32 = 16KB) into LDS, [kk][half][lane]x16B
// layout; per-lane-permuted global src, linear LDS dest (wave base + lane*16).
__device__ __forceinline__ void stage_tile(const char* __restrict__ xtile,
                                           char* ldsbuf, int wave, int lane) {
#pragma unroll
    for (int i = 0; i < 4; ++i) {
        int kk = i * 2 + (wave >> 1);
        const char* src = xtile + (lane & 15) * 1024 + (lane >> 4) * 32
                        + kk * 128 + (wave & 1) * 16;
        gld_lds16(src, ldsbuf + i * 4096 + wave * 1024);
    }
}

// Compute one tile from LDS, store its 16x16 output sub-tile (cols wave*16..).
__device__ __forceinline__ void compute_store(const char* buf,
                                              const bf16x8* wf,
                                              int lane, int lrow, int g, int wave,
                                              bf16_t* __restrict__ support,
                                              int tile) {
    f32x4 acc = {0.f, 0.f, 0.f, 0.f};
#pragma unroll
    for (int kk = 0; kk < 8; ++kk) {
        float4 lo = *(const float4*)(buf + kk * 2048 + lane * 16);
        float4 hi = *(const float4*)(buf + kk * 2048 + 1024 + lane * 16);
        acc = __builtin_amdgcn_mfma_f32_16x16x32_bf16(cvt8(lo, hi), wf[kk],
                                                      acc, 0, 0, 0);
    }
    bf16_t* __restrict__ sp = support + (size_t)tile * 16 * D_OUT
                            + wave * 16 + lrow;
#pragma unroll
    for (int q = 0; q < 4; ++q)
        sp[(g * 4 + q) * D_OUT] = (bf16_t)acc[q];
}

// ---------------------------------------------------------------------------
// Kernel 2 (fused): 1280 blocks, all GEMM role. Each block's edge chunk
// (1024 edges: hist atomics + rcv pack) runs in the prologue, hidden under
// the first stage's HBM latency. vmcnt FIFO: the counted vmcnt(4) in the
// loop retires edge ops with stage-0. x staged via double-buffered
// global_load_lds; W fragments in registers (one 16-col tile per wave).
// ---------------------------------------------------------------------------
__global__ __launch_bounds__(256, 5) void gemm_hist_cv(
        const float* __restrict__ x, const bf16x8* __restrict__ Wpack,
        bf16_t* __restrict__ support,
        const int* __restrict__ erow, const int* __restrict__ ecol,
        const float* __restrict__ eval,
        int* __restrict__ counts, unsigned* __restrict__ rcv) {
    __shared__ char xlds[2][16384];                // 32 KB double buffer
    int bid  = blockIdx.x;
    int lane = threadIdx.x & 63;
    int wave = threadIdx.x >> 6;
    int lrow = lane & 15;
    int g    = lane >> 4;

    // ---- edge chunk: histogram + rcv pack (oldest VMEM ops) ----
    {
        int e = (bid * 256 + threadIdx.x) * 4;     // 1280*1024 covers 1.2M
        if (e + 3 < N_EDGES) {
            int4   r4 = *(const int4*)(erow + e);
            int4   c4 = *(const int4*)(ecol + e);
            float4 v4 = *(const float4*)(eval + e);
            atomicAdd(&counts[r4.x], 1);
            atomicAdd(&counts[r4.y], 1);
            atomicAdd(&counts[r4.z], 1);
            atomicAdd(&counts[r4.w], 1);
            uint4 o1, o2;
            o1.x = pack_cv(c4.x, v4.x); o1.y = (unsigned)r4.x;
            o1.z = pack_cv(c4.y, v4.y); o1.w = (unsigned)r4.y;
            o2.x = pack_cv(c4.z, v4.z); o2.y = (unsigned)r4.z;
            o2.z = pack_cv(c4.w, v4.w); o2.w = (unsigned)r4.w;
            *(uint4*)(rcv + 2 * e)     = o1;
            *(uint4*)(rcv + 2 * e + 4) = o2;
        } else {
            for (int i = 0; i < 4; ++i) {
                if (e + i < N_EDGES) {
                    int rr = erow[e + i];
                    atomicAdd(&counts[rr], 1);
                    rcv[2 * (e + i)]     = pack_cv(ecol[e + i], eval[e + i]);
                    rcv[2 * (e + i) + 1] = (unsigned)rr;
                }
            }
        }
    }

    // ---- GEMM: stage tile0, load W frags, pipelined loop ----
    const char* xc = (const char*)x;
    int t = bid;                                   // bid in [0, NG)
    stage_tile(xc + (size_t)t * 16384, xlds[0], wave, lane);

    bf16x8 wf[8];
#pragma unroll
    for (int kk = 0; kk < 8; ++kk)
        wf[kk] = Wpack[(kk * 4 + wave) * 64 + lane];

    int cur = 0;
#pragma unroll 1
    for (; t < N_TILES; t += NG) {
        int nxt = t + NG;
        if (nxt < N_TILES) {
            stage_tile(xc + (size_t)nxt * 16384, xlds[cur ^ 1], wave, lane);
            asm volatile("s_waitcnt vmcnt(4)" ::: "memory");
        } else {
            asm volatile("s_waitcnt vmcnt(0)" ::: "memory");
        }
        __builtin_amdgcn_s_barrier();              // staged data visible
        __builtin_amdgcn_sched_barrier(0);         // pin ds_reads below
        compute_store(xlds[cur], wf, lane, lrow, g, wave, support, t);
        __builtin_amdgcn_s_barrier();              // all waves done reading
        __builtin_amdgcn_sched_barrier(0);         // pin next stage below
        cur ^= 1;
    }
}

// ---------------------------------------------------------------------------
// Kernel 3a: per-block partial sums of counts (1024 counts per block).
// ---------------------------------------------------------------------------
__global__ __launch_bounds__(256) void partial_k(const int* __restrict__ counts,
                                                 int* __restrict__ bsum) {
    int b = blockIdx.x, t = threadIdx.x;
    int base = b * SCAN_BLOCK + t * 4;
    int s = 0;
    if (base + 3 < N_NODES) {
        int4 v = *(const int4*)(counts + base);
        s = v.x + v.y + v.z + v.w;
    } else {
#pragma unroll
        for (int i = 0; i < 4; ++i)
            if (base + i < N_NODES) s += counts[base + i];
    }
#pragma unroll
    for (int off = 32; off > 0; off >>= 1) s += __shfl_down(s, off);
    __shared__ int sh[4];
    if ((t & 63) == 0) sh[t >> 6] = s;
    __syncthreads();
    if (t == 0) bsum[b] = sh[0] + sh[1] + sh[2] + sh[3];
}

// ---------------------------------------------------------------------------
// Kernel 3b: scan the 98 block sums (1 tiny block). Also writes offsets[N].
// ---------------------------------------------------------------------------
__global__ __launch_bounds__(128) void scan_bsum_k(const int* __restrict__ bsum,
                                                   int* __restrict__ bpre,
                                                   int* __restrict__ offsets) {
    __shared__ int sh[128];
    int t = threadIdx.x;
    int v = (t < SCAN_NB) ? bsum[t] : 0;
    sh[t] = v;
    __syncthreads();
    for (int off = 1; off < 128; off <<= 1) {
        int add = (t >= off) ? sh[t - off] : 0;
        __syncthreads();
        sh[t] += add;
        __syncthreads();
    }
    if (t < SCAN_NB) bpre[t] = sh[t] - v;
    if (t == 127) offsets[N_NODES] = sh[127];
}

// ---------------------------------------------------------------------------
// Kernel 3c: block-local scan + global prefix -> offsets, cursor.
// ---------------------------------------------------------------------------
__global__ __launch_bounds__(256) void emit_k(const int* __restrict__ counts,
                                              const int* __restrict__ bpre,
                                              int* __restrict__ offsets,
                                              int* __restrict__ cursor) {
    __shared__ int sh[256];
    int b = blockIdx.x, t = threadIdx.x;
    int base = b * SCAN_BLOCK + t * 4;
    int c0 = 0, c1 = 0, c2 = 0, c3 = 0;
    if (base + 3 < N_NODES) {
        int4 v = *(const int4*)(counts + base);
        c0 = v.x; c1 = v.y; c2 = v.z; c3 = v.w;
    } else {
        if (base + 0 < N_NODES) c0 = counts[base + 0];
        if (base + 1 < N_NODES) c1 = counts[base + 1];
        if (base + 2 < N_NODES) c2 = counts[base + 2];
        if (base + 3 < N_NODES) c3 = counts[base + 3];
    }
    int sum4 = c0 + c1 + c2 + c3;
    sh[t] = sum4;
    __syncthreads();
    for (int off = 1; off < 256; off <<= 1) {
        int add = (t >= off) ? sh[t - off] : 0;
        __syncthreads();
        sh[t] += add;
        __syncthreads();
    }
    int run = bpre[b] + sh[t] - sum4;
    if (base + 0 < N_NODES) { offsets[base + 0] = run; cursor[base + 0] = run; run += c0; }
    if (base + 1 < N_NODES) { offsets[base + 1] = run; cursor[base + 1] = run; run += c1; }
    if (base + 2 < N_NODES) { offsets[base + 2] = run; cursor[base + 2] = run; run += c2; }
    if (base + 3 < N_NODES) { offsets[base + 3] = run; cursor[base + 3] = run; run += c3; }
}

// ---------------------------------------------------------------------------
// Kernel 4: predicated CSR fill over packed rcv, one pass per row window.
// ---------------------------------------------------------------------------
__global__ __launch_bounds__(256) void fill_k(const unsigned* __restrict__ rcv,
                                              int* __restrict__ cursor,
                                              unsigned* __restrict__ csr,
                                              int lo, int hi) {
    int t = blockIdx.x * 256 + threadIdx.x;
    int e = t * 4;
    if (e + 3 < N_EDGES) {
        uint4 A = *(const uint4*)(rcv + 2 * e);
        uint4 B = *(const uint4*)(rcv + 2 * e + 4);
        int r0 = (int)A.y, r1 = (int)A.w, r2 = (int)B.y, r3 = (int)B.w;
        if (r0 >= lo && r0 < hi) { int q = atomicAdd(&cursor[r0], 1); csr[q] = A.x; }
        if (r1 >= lo && r1 < hi) { int q = atomicAdd(&cursor[r1], 1); csr[q] = A.z; }
        if (r2 >= lo && r2 < hi) { int q = atomicAdd(&cursor[r2], 1); csr[q] = B.x; }
        if (r3 >= lo && r3 < hi) { int q = atomicAdd(&cursor[r3], 1); csr[q] = B.z; }
    } else {
        for (int i = 0; i < 4; ++i) {
            if (e + i < N_EDGES) {
                unsigned cw = rcv[2 * (e + i)];
                int rr = (int)rcv[2 * (e + i) + 1];
                if (rr >= lo && rr < hi) {
                    int q = atomicAdd(&cursor[rr], 1);
                    csr[q] = cw;
                }
            }
        }
    }
}

// ---------------------------------------------------------------------------
// Kernel 5: aggregate + ReLU. 2 nodes/wave: half-wave (32 lanes) per node,
// lane = feature pair (bf16x2 4B gather -> 128B/half-wave coalesced).
// 8-deep ILP x 2 independent node streams = 16 outstanding gathers/wave.
// ---------------------------------------------------------------------------
__global__ __launch_bounds__(256) void agg_k(const int* __restrict__ offsets,
                                             const unsigned* __restrict__ csr,
                                             const unsigned* __restrict__ sup2,
                                             float* __restrict__ out) {
    int wave = threadIdx.x >> 6;
    int lane = threadIdx.x & 63;
    int half = lane >> 5;
    int fl   = lane & 31;
    int node = blockIdx.x * 8 + wave * 2 + half;
    if (node >= N_NODES) return;
    int s = offsets[node];
    int e = offsets[node + 1];
    const float inv = 1.f / 32767.f;
    float a0 = 0.f, a1 = 0.f;
    int p = s;
    for (; p + 8 <= e; p += 8) {
        unsigned w0 = csr[p + 0], w1 = csr[p + 1], w2 = csr[p + 2], w3 = csr[p + 3];
        unsigned w4 = csr[p + 4], w5 = csr[p + 5], w6 = csr[p + 6], w7 = csr[p + 7];
        unsigned q0 = sup2[(size_t)(w0 >> 15) * 32 + fl];
        unsigned q1 = sup2[(size_t)(w1 >> 15) * 32 + fl];
        unsigned q2 = sup2[(size_t)(w2 >> 15) * 32 + fl];
        unsigned q3 = sup2[(size_t)(w3 >> 15) * 32 + fl];
        unsigned q4 = sup2[(size_t)(w4 >> 15) * 32 + fl];
        unsigned q5 = sup2[(size_t)(w5 >> 15) * 32 + fl];
        unsigned q6 = sup2[(size_t)(w6 >> 15) * 32 + fl];
        unsigned q7 = sup2[(size_t)(w7 >> 15) * 32 + fl];
#define ACC(w, q) { float v = (float)((w) & 0x7fffu) * inv;                     \
        a0 = fmaf(v, __uint_as_float((q) << 16), a0);                           \
        a1 = fmaf(v, __uint_as_float((q) & 0xffff0000u), a1); }
        ACC(w0, q0) ACC(w1, q1) ACC(w2, q2) ACC(w3, q3)
        ACC(w4, q4) ACC(w5, q5) ACC(w6, q6) ACC(w7, q7)
    }
    for (; p + 4 <= e; p += 4) {
        unsigned w0 = csr[p + 0], w1 = csr[p + 1], w2 = csr[p + 2], w3 = csr[p + 3];
        unsigned q0 = sup2[(size_t)(w0 >> 15) * 32 + fl];
        unsigned q1 = sup2[(size_t)(w1 >> 15) * 32 + fl];
        unsigned q2 = sup2[(size_t)(w2 >> 15) * 32 + fl];
        unsigned q3 = sup2[(size_t)(w3 >> 15) * 32 + fl];
        ACC(w0, q0) ACC(w1, q1) ACC(w2, q2) ACC(w3, q3)
    }
    for (; p < e; ++p) {
        unsigned w = csr[p];
        unsigned q = sup2[(size_t)(w >> 15) * 32 + fl];
        ACC(w, q)
    }
#undef ACC
    float2 r;
    r.x = fmaxf(a0, 0.f);
    r.y = fmaxf(a1, 0.f);
    *(float2*)(out + (size_t)node * D_OUT + fl * 2) = r;
}

extern "C" void kernel_launch(void* const* d_in, const int* in_sizes, int n_in,
                              void* d_out, int out_size, void* d_ws, size_t ws_size,
                              hipStream_t stream) {
    const float* x    = (const float*)d_in[0];
    const int*   erow = (const int*)d_in[1];
    const int*   ecol = (const int*)d_in[2];
    const float* eval = (const float*)d_in[3];
    const float* W    = (const float*)d_in[4];
    float* out = (float*)d_out;

    // ---- workspace layout (16B-aligned segments, ~28.4 MB) ----
    char* ws = (char*)d_ws;
    bf16_t*   support = (bf16_t*)ws;                         // 12,800,000
    bf16_t*   WpackS  = (bf16_t*)(ws + 12800000);            //     32,768
    int*      counts  = (int*)(ws + 12832768);               //    400,000
    int*      offsets = (int*)(ws + 13232768);               //    400,004
    int*      cursor  = (int*)(ws + 13632896);               //    400,000
    unsigned* rcv     = (unsigned*)(ws + 14032896);          //  9,600,000
    unsigned* csr     = (unsigned*)(ws + 23632896);          //  4,800,000
    int*      bsum    = (int*)(ws + 28432896);               //        392
    int*      bpre    = (int*)(ws + 28433288);               //        392

    // 1) pack W into bf16 MFMA B-fragments
    pack_w<<<(D_IN * D_OUT + 255) / 256, 256, 0, stream>>>(W, WpackS);

    // 2) zero counts, then fused GEMM + edge prologue (hist + rcv pack)
    hipMemsetAsync(counts, 0, (size_t)N_NODES * sizeof(int), stream);
    gemm_hist_cv<<<NG, 256, 0, stream>>>(
        x, (const bf16x8*)WpackS, support, erow, ecol, eval, counts, rcv);

    // 3) hierarchical scan -> offsets, cursor
    partial_k<<<SCAN_NB, 256, 0, stream>>>(counts, bsum);
    scan_bsum_k<<<1, 128, 0, stream>>>(bsum, bpre, offsets);
    emit_k<<<SCAN_NB, 256, 0, stream>>>(counts, bpre, offsets, cursor);

    // 4) predicated CSR fill over rcv, 2 L2-localized passes
    for (int p = 0; p < FILL_PASSES; ++p) {
        fill_k<<<FILL_NB, 256, 0, stream>>>(rcv, cursor, csr,
                                            p * PASS_NODES, (p + 1) * PASS_NODES);
    }

    // 5) aggregate + ReLU (no atomics, writes every output element)
    agg_k<<<(N_NODES + 7) / 8, 256, 0, stream>>>(offsets, csr,
                                                 (const unsigned*)support, out);
}

// Round 12
// 131.521 us; speedup vs baseline: 1.4146x; 1.3083x over previous
//
#include <hip/hip_runtime.h>
#include <hip/hip_bf16.h>

#define N_NODES 100000
#define N_EDGES 1200000
#define D_IN 256
#define D_OUT 64
#define N_TILES (N_NODES / 16)                     // 6250 row tiles of 16

#define NG 1280                                    // GEMM blocks = 5/CU x 256
#define FILL_PASSES 2
#define PASS_NODES (N_NODES / FILL_PASSES)         // 50000
#define FILL_NB ((N_EDGES / 4 + 255) / 256)        // 1172

#define SCAN_BLOCK 1024
#define SCAN_NB ((N_NODES + SCAN_BLOCK - 1) / SCAN_BLOCK) // 98

typedef __bf16 bf16_t;
typedef bf16_t bf16x8 __attribute__((ext_vector_type(8)));
typedef float f32x4 __attribute__((ext_vector_type(4)));

// pack (col, val) into 4B: col<<15 | round(val*32767). val in [0,1).
__device__ __forceinline__ unsigned pack_cv(int col, float val) {
    return ((unsigned)col << 15) | (unsigned)(val * 32767.f + 0.5f);
}

__device__ __forceinline__ bf16x8 cvt8(float4 lo, float4 hi) {
    bf16x8 a;
    a[0] = (bf16_t)lo.x; a[1] = (bf16_t)lo.y;
    a[2] = (bf16_t)lo.z; a[3] = (bf16_t)lo.w;
    a[4] = (bf16_t)hi.x; a[5] = (bf16_t)hi.y;
    a[6] = (bf16_t)hi.z; a[7] = (bf16_t)hi.w;
    return a;
}

// async global->LDS, 16B per lane, dest = wave-uniform base + lane*16
__device__ __forceinline__ void gld_lds16(const void* g, void* l) {
    __builtin_amdgcn_global_load_lds(
        (const __attribute__((address_space(1))) void*)g,
        (__attribute__((address_space(3))) void*)l, 16, 0, 0);
}

// ---------------------------------------------------------------------------
// Kernel 1: pack W[256][64] (fp32) into MFMA B-fragment order, bf16.
// ---------------------------------------------------------------------------
__global__ __launch_bounds__(256) void pack_w(const float* __restrict__ W,
                                              bf16_t* __restrict__ Wpack) {
    int id = blockIdx.x * 256 + threadIdx.x;
    if (id < D_IN * D_OUT) {
        int i  = id & 7;
        int l  = (id >> 3) & 63;
        int n  = (id >> 9) & 3;
        int kk = id >> 11;
        int k = kk * 32 + (l >> 4) * 8 + i;
        int c = n * 16 + (l & 15);
        Wpack[id] = (bf16_t)W[k * D_OUT + c];
    }
}

// Stage one x tile (16 rows x 256 f32 = 16KB) into LDS, [kk][half][lane]x16B
// layout; per-lane-permuted global src, linear LDS dest (wave base + lane*16).
__device__ __forceinline__ void stage_tile(const char* __restrict__ xtile,
                                           char* ldsbuf, int wave, int lane) {
#pragma unroll
    for (int i = 0; i < 4; ++i) {
        int kk = i * 2 + (wave >> 1);
        const char* src = xtile + (lane & 15) * 1024 + (lane >> 4) * 32
                        + kk * 128 + (wave & 1) * 16;
        gld_lds16(src, ldsbuf + i * 4096 + wave * 1024);
    }
}

// Compute one tile from LDS, store its 16x16 output sub-tile (cols wave*16..).
__device__ __forceinline__ void compute_store(const char* buf,
                                              const bf16x8* wf,
                                              int lane, int lrow, int g, int wave,
                                              bf16_t* __restrict__ support,
                                              int tile) {
    f32x4 acc = {0.f, 0.f, 0.f, 0.f};
#pragma unroll
    for (int kk = 0; kk < 8; ++kk) {
        float4 lo = *(const float4*)(buf + kk * 2048 + lane * 16);
        float4 hi = *(const float4*)(buf + kk * 2048 + 1024 + lane * 16);
        acc = __builtin_amdgcn_mfma_f32_16x16x32_bf16(cvt8(lo, hi), wf[kk],
                                                      acc, 0, 0, 0);
    }
    bf16_t* __restrict__ sp = support + (size_t)tile * 16 * D_OUT
                            + wave * 16 + lrow;
#pragma unroll
    for (int q = 0; q < 4; ++q)
        sp[(g * 4 + q) * D_OUT] = (bf16_t)acc[q];
}

// ---------------------------------------------------------------------------
// Kernel 2 (fused): 1280 blocks. Order: issue stage-0's global_load_lds
// FIRST, then the edge chunk (hist atomics, capturing pos = old count,
// packed into rcv) runs in stage-0's HBM-latency shadow. Then the
// double-buffered GEMM loop (counted vmcnt(4), raw barriers).
// ---------------------------------------------------------------------------
__global__ __launch_bounds__(256, 5) void gemm_hist_cv(
        const float* __restrict__ x, const bf16x8* __restrict__ Wpack,
        bf16_t* __restrict__ support,
        const int* __restrict__ erow, const int* __restrict__ ecol,
        const float* __restrict__ eval,
        int* __restrict__ counts, unsigned* __restrict__ rcv) {
    __shared__ char xlds[2][16384];                // 32 KB double buffer
    int bid  = blockIdx.x;
    int lane = threadIdx.x & 63;
    int wave = threadIdx.x >> 6;
    int lrow = lane & 15;
    int g    = lane >> 4;

    // ---- issue stage-0 immediately (oldest VMEM ops) ----
    const char* xc = (const char*)x;
    int t = bid;                                   // bid in [0, NG)
    stage_tile(xc + (size_t)t * 16384, xlds[0], wave, lane);

    // ---- edge chunk in stage-0's shadow: hist + pos capture + rcv pack ----
    {
        int e = (bid * 256 + threadIdx.x) * 4;     // 1280*1024 covers 1.2M
        if (e + 3 < N_EDGES) {
            int4   r4 = *(const int4*)(erow + e);
            int4   c4 = *(const int4*)(ecol + e);
            float4 v4 = *(const float4*)(eval + e);
            unsigned p0 = (unsigned)atomicAdd(&counts[r4.x], 1);
            unsigned p1 = (unsigned)atomicAdd(&counts[r4.y], 1);
            unsigned p2 = (unsigned)atomicAdd(&counts[r4.z], 1);
            unsigned p3 = (unsigned)atomicAdd(&counts[r4.w], 1);
            uint4 o1, o2;
            o1.x = pack_cv(c4.x, v4.x); o1.y = (unsigned)r4.x | (p0 << 17);
            o1.z = pack_cv(c4.y, v4.y); o1.w = (unsigned)r4.y | (p1 << 17);
            o2.x = pack_cv(c4.z, v4.z); o2.y = (unsigned)r4.z | (p2 << 17);
            o2.z = pack_cv(c4.w, v4.w); o2.w = (unsigned)r4.w | (p3 << 17);
            *(uint4*)(rcv + 2 * e)     = o1;
            *(uint4*)(rcv + 2 * e + 4) = o2;
        } else {
            for (int i = 0; i < 4; ++i) {
                if (e + i < N_EDGES) {
                    int rr = erow[e + i];
                    unsigned pp = (unsigned)atomicAdd(&counts[rr], 1);
                    rcv[2 * (e + i)]     = pack_cv(ecol[e + i], eval[e + i]);
                    rcv[2 * (e + i) + 1] = (unsigned)rr | (pp << 17);
                }
            }
        }
    }

    // ---- W fragments (one 16-col tile per wave) ----
    bf16x8 wf[8];
#pragma unroll
    for (int kk = 0; kk < 8; ++kk)
        wf[kk] = Wpack[(kk * 4 + wave) * 64 + lane];

    // ---- pipelined GEMM loop ----
    int cur = 0;
#pragma unroll 1
    for (; t < N_TILES; t += NG) {
        int nxt = t + NG;
        if (nxt < N_TILES) {
            stage_tile(xc + (size_t)nxt * 16384, xlds[cur ^ 1], wave, lane);
            asm volatile("s_waitcnt vmcnt(4)" ::: "memory");
        } else {
            asm volatile("s_waitcnt vmcnt(0)" ::: "memory");
        }
        __builtin_amdgcn_s_barrier();              // staged data visible
        __builtin_amdgcn_sched_barrier(0);         // pin ds_reads below
        compute_store(xlds[cur], wf, lane, lrow, g, wave, support, t);
        __builtin_amdgcn_s_barrier();              // all waves done reading
        __builtin_amdgcn_sched_barrier(0);         // pin next stage below
        cur ^= 1;
    }
}

// ---------------------------------------------------------------------------
// Kernel 3a: per-block partial sums of ceil4(counts) (quad-aligned segments).
// ---------------------------------------------------------------------------
__global__ __launch_bounds__(256) void partial_k(const int* __restrict__ counts,
                                                 int* __restrict__ bsum) {
    int b = blockIdx.x, t = threadIdx.x;
    int base = b * SCAN_BLOCK + t * 4;
    int s = 0;
    if (base + 3 < N_NODES) {
        int4 v = *(const int4*)(counts + base);
        s = ((v.x + 3) & ~3) + ((v.y + 3) & ~3) + ((v.z + 3) & ~3) + ((v.w + 3) & ~3);
    } else {
#pragma unroll
        for (int i = 0; i < 4; ++i)
            if (base + i < N_NODES) s += (counts[base + i] + 3) & ~3;
    }
#pragma unroll
    for (int off = 32; off > 0; off >>= 1) s += __shfl_down(s, off);
    __shared__ int sh[4];
    if ((t & 63) == 0) sh[t >> 6] = s;
    __syncthreads();
    if (t == 0) bsum[b] = sh[0] + sh[1] + sh[2] + sh[3];
}

// ---------------------------------------------------------------------------
// Kernel 3b: scan the 98 block sums (1 tiny block).
// ---------------------------------------------------------------------------
__global__ __launch_bounds__(128) void scan_bsum_k(const int* __restrict__ bsum,
                                                   int* __restrict__ bpre,
                                                   int* __restrict__ offsets) {
    __shared__ int sh[128];
    int t = threadIdx.x;
    int v = (t < SCAN_NB) ? bsum[t] : 0;
    sh[t] = v;
    __syncthreads();
    for (int off = 1; off < 128; off <<= 1) {
        int add = (t >= off) ? sh[t - off] : 0;
        __syncthreads();
        sh[t] += add;
        __syncthreads();
    }
    if (t < SCAN_NB) bpre[t] = sh[t] - v;
    if (t == 127) offsets[N_NODES] = sh[127];
}

// ---------------------------------------------------------------------------
// Kernel 3c: block-local scan (ceil4 degrees) + global prefix -> offsets.
// ---------------------------------------------------------------------------
__global__ __launch_bounds__(256) void emit_k(const int* __restrict__ counts,
                                              const int* __restrict__ bpre,
                                              int* __restrict__ offsets) {
    __shared__ int sh[256];
    int b = blockIdx.x, t = threadIdx.x;
    int base = b * SCAN_BLOCK + t * 4;
    int c0 = 0, c1 = 0, c2 = 0, c3 = 0;
    if (base + 3 < N_NODES) {
        int4 v = *(const int4*)(counts + base);
        c0 = (v.x + 3) & ~3; c1 = (v.y + 3) & ~3;
        c2 = (v.z + 3) & ~3; c3 = (v.w + 3) & ~3;
    } else {
        if (base + 0 < N_NODES) c0 = (counts[base + 0] + 3) & ~3;
        if (base + 1 < N_NODES) c1 = (counts[base + 1] + 3) & ~3;
        if (base + 2 < N_NODES) c2 = (counts[base + 2] + 3) & ~3;
        if (base + 3 < N_NODES) c3 = (counts[base + 3] + 3) & ~3;
    }
    int sum4 = c0 + c1 + c2 + c3;
    sh[t] = sum4;
    __syncthreads();
    for (int off = 1; off < 256; off <<= 1) {
        int add = (t >= off) ? sh[t - off] : 0;
        __syncthreads();
        sh[t] += add;
        __syncthreads();
    }
    int run = bpre[b] + sh[t] - sum4;
    if (base + 0 < N_NODES) { offsets[base + 0] = run; run += c0; }
    if (base + 1 < N_NODES) { offsets[base + 1] = run; run += c1; }
    if (base + 2 < N_NODES) { offsets[base + 2] = run; run += c2; }
    if (base + 3 < N_NODES) { offsets[base + 3] = run; run += c3; }
}

// ---------------------------------------------------------------------------
// Kernel 4: atomic-free predicated CSR fill: dst = offsets[row] + pos.
// 4 independent offsets gathers in flight; plain stores into the L2-resident
// csr window [lo, hi).
// ---------------------------------------------------------------------------
__global__ __launch_bounds__(256) void fill_k(const unsigned* __restrict__ rcv,
                                              const int* __restrict__ offsets,
                                              unsigned* __restrict__ csr,
                                              int lo, int hi) {
    int t = blockIdx.x * 256 + threadIdx.x;
    int e = t * 4;
    if (e + 3 < N_EDGES) {
        uint4 A = *(const uint4*)(rcv + 2 * e);
        uint4 B = *(const uint4*)(rcv + 2 * e + 4);
        int r0 = (int)(A.y & 0x1ffffu), p0 = (int)(A.y >> 17);
        int r1 = (int)(A.w & 0x1ffffu), p1 = (int)(A.w >> 17);
        int r2 = (int)(B.y & 0x1ffffu), p2 = (int)(B.y >> 17);
        int r3 = (int)(B.w & 0x1ffffu), p3 = (int)(B.w >> 17);
        int o0 = offsets[r0];
        int o1 = offsets[r1];
        int o2 = offsets[r2];
        int o3 = offsets[r3];
        if (r0 >= lo && r0 < hi) csr[o0 + p0] = A.x;
        if (r1 >= lo && r1 < hi) csr[o1 + p1] = A.z;
        if (r2 >= lo && r2 < hi) csr[o2 + p2] = B.x;
        if (r3 >= lo && r3 < hi) csr[o3 + p3] = B.z;
    } else {
        for (int i = 0; i < 4; ++i) {
            if (e + i < N_EDGES) {
                unsigned cw = rcv[2 * (e + i)];
                unsigned rw = rcv[2 * (e + i) + 1];
                int rr = (int)(rw & 0x1ffffu);
                int pp = (int)(rw >> 17);
                if (rr >= lo && rr < hi) csr[offsets[rr] + pp] = cw;
            }
        }
    }
}

// ---------------------------------------------------------------------------
// Kernel 5: aggregate + ReLU. 2 nodes/wave (half-wave per node, lane =
// bf16x2 feature pair). CSR segments are 16B-aligned -> uint4 csr loads
// (2 ops per 8 edges). counts[] gives true degree.
// ---------------------------------------------------------------------------
__global__ __launch_bounds__(256) void agg_k(const int* __restrict__ offsets,
                                             const int* __restrict__ counts,
                                             const unsigned* __restrict__ csr,
                                             const unsigned* __restrict__ sup2,
                                             float* __restrict__ out) {
    int wave = threadIdx.x >> 6;
    int lane = threadIdx.x & 63;
    int half = lane >> 5;
    int fl   = lane & 31;
    int node = blockIdx.x * 8 + wave * 2 + half;
    if (node >= N_NODES) return;
    int s   = offsets[node];
    int cnt = counts[node];
    int e   = s + cnt;
    const float inv = 1.f / 32767.f;
    float a0 = 0.f, a1 = 0.f;
    int p = s;
#define ACC(w, q) { float v = (float)((w) & 0x7fffu) * inv;                     \
        a0 = fmaf(v, __uint_as_float((q) << 16), a0);                           \
        a1 = fmaf(v, __uint_as_float((q) & 0xffff0000u), a1); }
    for (; p + 8 <= e; p += 8) {
        uint4 A = *(const uint4*)(csr + p);
        uint4 B = *(const uint4*)(csr + p + 4);
        unsigned q0 = sup2[(size_t)(A.x >> 15) * 32 + fl];
        unsigned q1 = sup2[(size_t)(A.y >> 15) * 32 + fl];
        unsigned q2 = sup2[(size_t)(A.z >> 15) * 32 + fl];
        unsigned q3 = sup2[(size_t)(A.w >> 15) * 32 + fl];
        unsigned q4 = sup2[(size_t)(B.x >> 15) * 32 + fl];
        unsigned q5 = sup2[(size_t)(B.y >> 15) * 32 + fl];
        unsigned q6 = sup2[(size_t)(B.z >> 15) * 32 + fl];
        unsigned q7 = sup2[(size_t)(B.w >> 15) * 32 + fl];
        ACC(A.x, q0) ACC(A.y, q1) ACC(A.z, q2) ACC(A.w, q3)
        ACC(B.x, q4) ACC(B.y, q5) ACC(B.z, q6) ACC(B.w, q7)
    }
    if (p + 4 <= e) {
        uint4 A = *(const uint4*)(csr + p);
        unsigned q0 = sup2[(size_t)(A.x >> 15) * 32 + fl];
        unsigned q1 = sup2[(size_t)(A.y >> 15) * 32 + fl];
        unsigned q2 = sup2[(size_t)(A.z >> 15) * 32 + fl];
        unsigned q3 = sup2[(size_t)(A.w >> 15) * 32 + fl];
        ACC(A.x, q0) ACC(A.y, q1) ACC(A.z, q2) ACC(A.w, q3)
        p += 4;
    }
    for (; p < e; ++p) {
        unsigned w = csr[p];
        unsigned q = sup2[(size_t)(w >> 15) * 32 + fl];
        ACC(w, q)
    }
#undef ACC
    float2 r;
    r.x = fmaxf(a0, 0.f);
    r.y = fmaxf(a1, 0.f);
    *(float2*)(out + (size_t)node * D_OUT + fl * 2) = r;
}

extern "C" void kernel_launch(void* const* d_in, const int* in_sizes, int n_in,
                              void* d_out, int out_size, void* d_ws, size_t ws_size,
                              hipStream_t stream) {
    const float* x    = (const float*)d_in[0];
    const int*   erow = (const int*)d_in[1];
    const int*   ecol = (const int*)d_in[2];
    const float* eval = (const float*)d_in[3];
    const float* W    = (const float*)d_in[4];
    float* out = (float*)d_out;

    // ---- workspace layout (16B-aligned segments, ~29.3 MB) ----
    char* ws = (char*)d_ws;
    bf16_t*   support = (bf16_t*)ws;                         // 12,800,000
    bf16_t*   WpackS  = (bf16_t*)(ws + 12800000);            //     32,768
    int*      counts  = (int*)(ws + 12832768);               //    400,000
    int*      offsets = (int*)(ws + 13232768);               //    400,004 (+pad)
    unsigned* rcv     = (unsigned*)(ws + 13632784);          //  9,600,000
    unsigned* csr     = (unsigned*)(ws + 23232784);          //  6,000,000 (padded)
    int*      bsum    = (int*)(ws + 29232784);               //        392
    int*      bpre    = (int*)(ws + 29233184);               //        392

    // 1) pack W into bf16 MFMA B-fragments
    pack_w<<<(D_IN * D_OUT + 255) / 256, 256, 0, stream>>>(W, WpackS);

    // 2) zero counts, then fused GEMM + edge chunk (hist + pos + rcv pack)
    hipMemsetAsync(counts, 0, (size_t)N_NODES * sizeof(int), stream);
    gemm_hist_cv<<<NG, 256, 0, stream>>>(
        x, (const bf16x8*)WpackS, support, erow, ecol, eval, counts, rcv);

    // 3) hierarchical scan (ceil4 degrees) -> quad-aligned offsets
    partial_k<<<SCAN_NB, 256, 0, stream>>>(counts, bsum);
    scan_bsum_k<<<1, 128, 0, stream>>>(bsum, bpre, offsets);
    emit_k<<<SCAN_NB, 256, 0, stream>>>(counts, bpre, offsets);

    // 4) atomic-free predicated CSR fill, 2 L2-localized passes
    for (int p = 0; p < FILL_PASSES; ++p) {
        fill_k<<<FILL_NB, 256, 0, stream>>>(rcv, offsets, csr,
                                            p * PASS_NODES, (p + 1) * PASS_NODES);
    }

    // 5) aggregate + ReLU (no atomics, writes every output element)
    agg_k<<<(N_NODES + 7) / 8, 256, 0, stream>>>(offsets, counts, csr,
                                                 (const unsigned*)support, out);
}

// Round 13
// 125.752 us; speedup vs baseline: 1.4795x; 1.0459x over previous
//
#include <hip/hip_runtime.h>
#include <hip/hip_bf16.h>

#define N_NODES 100000
#define N_EDGES 1200000
#define D_IN 256
#define D_OUT 64
#define N_TILES (N_NODES / 16)                     // 6250 row tiles of 16

#define NG 1280                                    // GEMM blocks = 5/CU x 256
#define FUSED_NB (NG * 2)                          // even: GEMM, odd: edge
#define EDGE4_NB ((N_EDGES / 4 + 255) / 256)       // 1172 (4 edges/thread)

#define FILL_PASSES 2
#define PASS_NODES (N_NODES / FILL_PASSES)         // 50000
#define FILL_NB ((N_EDGES / 4 + 255) / 256)        // 1172

#define SCAN_BLOCK 1024
#define SCAN_NB ((N_NODES + SCAN_BLOCK - 1) / SCAN_BLOCK) // 98

typedef __bf16 bf16_t;
typedef bf16_t bf16x8 __attribute__((ext_vector_type(8)));
typedef float f32x4 __attribute__((ext_vector_type(4)));

// pack (col, val) into 4B: col<<15 | round(val*32767). val in [0,1).
__device__ __forceinline__ unsigned pack_cv(int col, float val) {
    return ((unsigned)col << 15) | (unsigned)(val * 32767.f + 0.5f);
}

__device__ __forceinline__ bf16x8 cvt8(float4 lo, float4 hi) {
    bf16x8 a;
    a[0] = (bf16_t)lo.x; a[1] = (bf16_t)lo.y;
    a[2] = (bf16_t)lo.z; a[3] = (bf16_t)lo.w;
    a[4] = (bf16_t)hi.x; a[5] = (bf16_t)hi.y;
    a[6] = (bf16_t)hi.z; a[7] = (bf16_t)hi.w;
    return a;
}

// async global->LDS, 16B per lane, dest = wave-uniform base + lane*16
__device__ __forceinline__ void gld_lds16(const void* g, void* l) {
    __builtin_amdgcn_global_load_lds(
        (const __attribute__((address_space(1))) void*)g,
        (__attribute__((address_space(3))) void*)l, 16, 0, 0);
}

// ---------------------------------------------------------------------------
// Kernel 1: pack W[256][64] (fp32) into MFMA B-fragment order, bf16.
// ---------------------------------------------------------------------------
__global__ __launch_bounds__(256) void pack_w(const float* __restrict__ W,
                                              bf16_t* __restrict__ Wpack) {
    int id = blockIdx.x * 256 + threadIdx.x;
    if (id < D_IN * D_OUT) {
        int i  = id & 7;
        int l  = (id >> 3) & 63;
        int n  = (id >> 9) & 3;
        int kk = id >> 11;
        int k = kk * 32 + (l >> 4) * 8 + i;
        int c = n * 16 + (l & 15);
        Wpack[id] = (bf16_t)W[k * D_OUT + c];
    }
}

// Stage one x tile (16 rows x 256 f32 = 16KB) into LDS, [kk][half][lane]x16B
// layout; per-lane-permuted global src, linear LDS dest (wave base + lane*16).
__device__ __forceinline__ void stage_tile(const char* __restrict__ xtile,
                                           char* ldsbuf, int wave, int lane) {
#pragma unroll
    for (int i = 0; i < 4; ++i) {
        int kk = i * 2 + (wave >> 1);
        const char* src = xtile + (lane & 15) * 1024 + (lane >> 4) * 32
                        + kk * 128 + (wave & 1) * 16;
        gld_lds16(src, ldsbuf + i * 4096 + wave * 1024);
    }
}

// Compute one tile from LDS, store its 16x16 output sub-tile (cols wave*16..).
__device__ __forceinline__ void compute_store(const char* buf,
                                              const bf16x8* wf,
                                              int lane, int lrow, int g, int wave,
                                              bf16_t* __restrict__ support,
                                              int tile) {
    f32x4 acc = {0.f, 0.f, 0.f, 0.f};
#pragma unroll
    for (int kk = 0; kk < 8; ++kk) {
        float4 lo = *(const float4*)(buf + kk * 2048 + lane * 16);
        float4 hi = *(const float4*)(buf + kk * 2048 + 1024 + lane * 16);
        acc = __builtin_amdgcn_mfma_f32_16x16x32_bf16(cvt8(lo, hi), wf[kk],
                                                      acc, 0, 0, 0);
    }
    bf16_t* __restrict__ sp = support + (size_t)tile * 16 * D_OUT
                            + wave * 16 + lrow;
#pragma unroll
    for (int q = 0; q < 4; ++q)
        sp[(g * 4 + q) * D_OUT] = (bf16_t)acc[q];
}

// ---------------------------------------------------------------------------
// Kernel 2 (fused, role-split — R10 structure): even blocks = GEMM
// (double-buffered global_load_lds pipeline, counted vmcnt(4), raw
// barriers); odd blocks = edge chunk (hist atomics capturing pos, rcv
// pack). Edge blocks co-schedule with GEMM blocks at CU level instead of
// serializing in-wave (R11/R12's prologue cost ~15 us vs this).
// ---------------------------------------------------------------------------
__global__ __launch_bounds__(256, 5) void gemm_hist_cv(
        const float* __restrict__ x, const bf16x8* __restrict__ Wpack,
        bf16_t* __restrict__ support,
        const int* __restrict__ erow, const int* __restrict__ ecol,
        const float* __restrict__ eval,
        int* __restrict__ counts, unsigned* __restrict__ rcv) {
    __shared__ char xlds[2][16384];                // 32 KB double buffer
    int bid  = blockIdx.x;
    int role = bid & 1;
    int idx  = bid >> 1;
    if (role == 0) {
        // ---------------- GEMM role ----------------
        int lane = threadIdx.x & 63;
        int wave = threadIdx.x >> 6;
        int lrow = lane & 15;
        int g    = lane >> 4;

        const char* xc = (const char*)x;
        int t = idx;                               // idx in [0, NG)
        stage_tile(xc + (size_t)t * 16384, xlds[0], wave, lane);

        bf16x8 wf[8];
#pragma unroll
        for (int kk = 0; kk < 8; ++kk)
            wf[kk] = Wpack[(kk * 4 + wave) * 64 + lane];

        int cur = 0;
#pragma unroll 1
        for (; t < N_TILES; t += NG) {
            int nxt = t + NG;
            if (nxt < N_TILES) {
                stage_tile(xc + (size_t)nxt * 16384, xlds[cur ^ 1], wave, lane);
                asm volatile("s_waitcnt vmcnt(4)" ::: "memory");
            } else {
                asm volatile("s_waitcnt vmcnt(0)" ::: "memory");
            }
            __builtin_amdgcn_s_barrier();          // staged data visible
            __builtin_amdgcn_sched_barrier(0);     // pin ds_reads below
            compute_store(xlds[cur], wf, lane, lrow, g, wave, support, t);
            __builtin_amdgcn_s_barrier();          // all waves done reading
            __builtin_amdgcn_sched_barrier(0);     // pin next stage below
            cur ^= 1;
        }
    } else {
        // ---- edge role: histogram + pos capture + rcv pack ----
        if (idx >= EDGE4_NB) return;
        int e = (idx * 256 + threadIdx.x) * 4;
        if (e + 3 < N_EDGES) {
            int4   r4 = *(const int4*)(erow + e);
            int4   c4 = *(const int4*)(ecol + e);
            float4 v4 = *(const float4*)(eval + e);
            unsigned p0 = (unsigned)atomicAdd(&counts[r4.x], 1);
            unsigned p1 = (unsigned)atomicAdd(&counts[r4.y], 1);
            unsigned p2 = (unsigned)atomicAdd(&counts[r4.z], 1);
            unsigned p3 = (unsigned)atomicAdd(&counts[r4.w], 1);
            uint4 o1, o2;
            o1.x = pack_cv(c4.x, v4.x); o1.y = (unsigned)r4.x | (p0 << 17);
            o1.z = pack_cv(c4.y, v4.y); o1.w = (unsigned)r4.y | (p1 << 17);
            o2.x = pack_cv(c4.z, v4.z); o2.y = (unsigned)r4.z | (p2 << 17);
            o2.z = pack_cv(c4.w, v4.w); o2.w = (unsigned)r4.w | (p3 << 17);
            *(uint4*)(rcv + 2 * e)     = o1;
            *(uint4*)(rcv + 2 * e + 4) = o2;
        } else {
            for (int i = 0; i < 4; ++i) {
                if (e + i < N_EDGES) {
                    int rr = erow[e + i];
                    unsigned pp = (unsigned)atomicAdd(&counts[rr], 1);
                    rcv[2 * (e + i)]     = pack_cv(ecol[e + i], eval[e + i]);
                    rcv[2 * (e + i) + 1] = (unsigned)rr | (pp << 17);
                }
            }
        }
    }
}

// ---------------------------------------------------------------------------
// Kernel 3a: per-block partial sums of ceil4(counts) (quad-aligned segments).
// ---------------------------------------------------------------------------
__global__ __launch_bounds__(256) void partial_k(const int* __restrict__ counts,
                                                 int* __restrict__ bsum) {
    int b = blockIdx.x, t = threadIdx.x;
    int base = b * SCAN_BLOCK + t * 4;
    int s = 0;
    if (base + 3 < N_NODES) {
        int4 v = *(const int4*)(counts + base);
        s = ((v.x + 3) & ~3) + ((v.y + 3) & ~3) + ((v.z + 3) & ~3) + ((v.w + 3) & ~3);
    } else {
#pragma unroll
        for (int i = 0; i < 4; ++i)
            if (base + i < N_NODES) s += (counts[base + i] + 3) & ~3;
    }
#pragma unroll
    for (int off = 32; off > 0; off >>= 1) s += __shfl_down(s, off);
    __shared__ int sh[4];
    if ((t & 63) == 0) sh[t >> 6] = s;
    __syncthreads();
    if (t == 0) bsum[b] = sh[0] + sh[1] + sh[2] + sh[3];
}

// ---------------------------------------------------------------------------
// Kernel 3b: scan the 98 block sums (1 tiny block).
// ---------------------------------------------------------------------------
__global__ __launch_bounds__(128) void scan_bsum_k(const int* __restrict__ bsum,
                                                   int* __restrict__ bpre,
                                                   int* __restrict__ offsets) {
    __shared__ int sh[128];
    int t = threadIdx.x;
    int v = (t < SCAN_NB) ? bsum[t] : 0;
    sh[t] = v;
    __syncthreads();
    for (int off = 1; off < 128; off <<= 1) {
        int add = (t >= off) ? sh[t - off] : 0;
        __syncthreads();
        sh[t] += add;
        __syncthreads();
    }
    if (t < SCAN_NB) bpre[t] = sh[t] - v;
    if (t == 127) offsets[N_NODES] = sh[127];
}

// ---------------------------------------------------------------------------
// Kernel 3c: block-local scan (ceil4 degrees) + global prefix -> offsets.
// ---------------------------------------------------------------------------
__global__ __launch_bounds__(256) void emit_k(const int* __restrict__ counts,
                                              const int* __restrict__ bpre,
                                              int* __restrict__ offsets) {
    __shared__ int sh[256];
    int b = blockIdx.x, t = threadIdx.x;
    int base = b * SCAN_BLOCK + t * 4;
    int c0 = 0, c1 = 0, c2 = 0, c3 = 0;
    if (base + 3 < N_NODES) {
        int4 v = *(const int4*)(counts + base);
        c0 = (v.x + 3) & ~3; c1 = (v.y + 3) & ~3;
        c2 = (v.z + 3) & ~3; c3 = (v.w + 3) & ~3;
    } else {
        if (base + 0 < N_NODES) c0 = (counts[base + 0] + 3) & ~3;
        if (base + 1 < N_NODES) c1 = (counts[base + 1] + 3) & ~3;
        if (base + 2 < N_NODES) c2 = (counts[base + 2] + 3) & ~3;
        if (base + 3 < N_NODES) c3 = (counts[base + 3] + 3) & ~3;
    }
    int sum4 = c0 + c1 + c2 + c3;
    sh[t] = sum4;
    __syncthreads();
    for (int off = 1; off < 256; off <<= 1) {
        int add = (t >= off) ? sh[t - off] : 0;
        __syncthreads();
        sh[t] += add;
        __syncthreads();
    }
    int run = bpre[b] + sh[t] - sum4;
    if (base + 0 < N_NODES) { offsets[base + 0] = run; run += c0; }
    if (base + 1 < N_NODES) { offsets[base + 1] = run; run += c1; }
    if (base + 2 < N_NODES) { offsets[base + 2] = run; run += c2; }
    if (base + 3 < N_NODES) { offsets[base + 3] = run; run += c3; }
}

// ---------------------------------------------------------------------------
// Kernel 4: atomic-free predicated CSR fill: dst = offsets[row] + pos.
// 4 independent offsets gathers in flight; plain stores into the
// L2-resident csr window [lo, hi).
// ---------------------------------------------------------------------------
__global__ __launch_bounds__(256) void fill_k(const unsigned* __restrict__ rcv,
                                              const int* __restrict__ offsets,
                                              unsigned* __restrict__ csr,
                                              int lo, int hi) {
    int t = blockIdx.x * 256 + threadIdx.x;
    int e = t * 4;
    if (e + 3 < N_EDGES) {
        uint4 A = *(const uint4*)(rcv + 2 * e);
        uint4 B = *(const uint4*)(rcv + 2 * e + 4);
        int r0 = (int)(A.y & 0x1ffffu), p0 = (int)(A.y >> 17);
        int r1 = (int)(A.w & 0x1ffffu), p1 = (int)(A.w >> 17);
        int r2 = (int)(B.y & 0x1ffffu), p2 = (int)(B.y >> 17);
        int r3 = (int)(B.w & 0x1ffffu), p3 = (int)(B.w >> 17);
        int o0 = offsets[r0];
        int o1 = offsets[r1];
        int o2 = offsets[r2];
        int o3 = offsets[r3];
        if (r0 >= lo && r0 < hi) csr[o0 + p0] = A.x;
        if (r1 >= lo && r1 < hi) csr[o1 + p1] = A.z;
        if (r2 >= lo && r2 < hi) csr[o2 + p2] = B.x;
        if (r3 >= lo && r3 < hi) csr[o3 + p3] = B.z;
    } else {
        for (int i = 0; i < 4; ++i) {
            if (e + i < N_EDGES) {
                unsigned cw = rcv[2 * (e + i)];
                unsigned rw = rcv[2 * (e + i) + 1];
                int rr = (int)(rw & 0x1ffffu);
                int pp = (int)(rw >> 17);
                if (rr >= lo && rr < hi) csr[offsets[rr] + pp] = cw;
            }
        }
    }
}

// ---------------------------------------------------------------------------
// Kernel 5: aggregate + ReLU. 2 nodes/wave (half-wave per node, lane =
// bf16x2 feature pair). CSR segments are 16B-aligned -> uint4 csr loads.
// ---------------------------------------------------------------------------
__global__ __launch_bounds__(256) void agg_k(const int* __restrict__ offsets,
                                             const int* __restrict__ counts,
                                             const unsigned* __restrict__ csr,
                                             const unsigned* __restrict__ sup2,
                                             float* __restrict__ out) {
    int wave = threadIdx.x >> 6;
    int lane = threadIdx.x & 63;
    int half = lane >> 5;
    int fl   = lane & 31;
    int node = blockIdx.x * 8 + wave * 2 + half;
    if (node >= N_NODES) return;
    int s   = offsets[node];
    int cnt = counts[node];
    int e   = s + cnt;
    const float inv = 1.f / 32767.f;
    float a0 = 0.f, a1 = 0.f;
    int p = s;
#define ACC(w, q) { float v = (float)((w) & 0x7fffu) * inv;                     \
        a0 = fmaf(v, __uint_as_float((q) << 16), a0);                           \
        a1 = fmaf(v, __uint_as_float((q) & 0xffff0000u), a1); }
    for (; p + 8 <= e; p += 8) {
        uint4 A = *(const uint4*)(csr + p);
        uint4 B = *(const uint4*)(csr + p + 4);
        unsigned q0 = sup2[(size_t)(A.x >> 15) * 32 + fl];
        unsigned q1 = sup2[(size_t)(A.y >> 15) * 32 + fl];
        unsigned q2 = sup2[(size_t)(A.z >> 15) * 32 + fl];
        unsigned q3 = sup2[(size_t)(A.w >> 15) * 32 + fl];
        unsigned q4 = sup2[(size_t)(B.x >> 15) * 32 + fl];
        unsigned q5 = sup2[(size_t)(B.y >> 15) * 32 + fl];
        unsigned q6 = sup2[(size_t)(B.z >> 15) * 32 + fl];
        unsigned q7 = sup2[(size_t)(B.w >> 15) * 32 + fl];
        ACC(A.x, q0) ACC(A.y, q1) ACC(A.z, q2) ACC(A.w, q3)
        ACC(B.x, q4) ACC(B.y, q5) ACC(B.z, q6) ACC(B.w, q7)
    }
    if (p + 4 <= e) {
        uint4 A = *(const uint4*)(csr + p);
        unsigned q0 = sup2[(size_t)(A.x >> 15) * 32 + fl];
        unsigned q1 = sup2[(size_t)(A.y >> 15) * 32 + fl];
        unsigned q2 = sup2[(size_t)(A.z >> 15) * 32 + fl];
        unsigned q3 = sup2[(size_t)(A.w >> 15) * 32 + fl];
        ACC(A.x, q0) ACC(A.y, q1) ACC(A.z, q2) ACC(A.w, q3)
        p += 4;
    }
    for (; p < e; ++p) {
        unsigned w = csr[p];
        unsigned q = sup2[(size_t)(w >> 15) * 32 + fl];
        ACC(w, q)
    }
#undef ACC
    float2 r;
    r.x = fmaxf(a0, 0.f);
    r.y = fmaxf(a1, 0.f);
    *(float2*)(out + (size_t)node * D_OUT + fl * 2) = r;
}

extern "C" void kernel_launch(void* const* d_in, const int* in_sizes, int n_in,
                              void* d_out, int out_size, void* d_ws, size_t ws_size,
                              hipStream_t stream) {
    const float* x    = (const float*)d_in[0];
    const int*   erow = (const int*)d_in[1];
    const int*   ecol = (const int*)d_in[2];
    const float* eval = (const float*)d_in[3];
    const float* W    = (const float*)d_in[4];
    float* out = (float*)d_out;

    // ---- workspace layout (16B-aligned segments, ~29.3 MB) ----
    char* ws = (char*)d_ws;
    bf16_t*   support = (bf16_t*)ws;                         // 12,800,000
    bf16_t*   WpackS  = (bf16_t*)(ws + 12800000);            //     32,768
    int*      counts  = (int*)(ws + 12832768);               //    400,000
    int*      offsets = (int*)(ws + 13232768);               //    400,004 (+pad)
    unsigned* rcv     = (unsigned*)(ws + 13632784);          //  9,600,000
    unsigned* csr     = (unsigned*)(ws + 23232784);          //  6,000,000 (padded)
    int*      bsum    = (int*)(ws + 29232784);               //        392
    int*      bpre    = (int*)(ws + 29233184);               //        392

    // 1) pack W into bf16 MFMA B-fragments
    pack_w<<<(D_IN * D_OUT + 255) / 256, 256, 0, stream>>>(W, WpackS);

    // 2) zero counts, then fused role-split GEMM + edge (hist + pos + rcv)
    hipMemsetAsync(counts, 0, (size_t)N_NODES * sizeof(int), stream);
    gemm_hist_cv<<<FUSED_NB, 256, 0, stream>>>(
        x, (const bf16x8*)WpackS, support, erow, ecol, eval, counts, rcv);

    // 3) hierarchical scan (ceil4 degrees) -> quad-aligned offsets
    partial_k<<<SCAN_NB, 256, 0, stream>>>(counts, bsum);
    scan_bsum_k<<<1, 128, 0, stream>>>(bsum, bpre, offsets);
    emit_k<<<SCAN_NB, 256, 0, stream>>>(counts, bpre, offsets);

    // 4) atomic-free predicated CSR fill, 2 L2-localized passes
    for (int p = 0; p < FILL_PASSES; ++p) {
        fill_k<<<FILL_NB, 256, 0, stream>>>(rcv, offsets, csr,
                                            p * PASS_NODES, (p + 1) * PASS_NODES);
    }

    // 5) aggregate + ReLU (no atomics, writes every output element)
    agg_k<<<(N_NODES + 7) / 8, 256, 0, stream>>>(offsets, counts, csr,
                                                 (const unsigned*)support, out);
}

// Round 14
// 121.591 us; speedup vs baseline: 1.5302x; 1.0342x over previous
//
#include <hip/hip_runtime.h>
#include <hip/hip_bf16.h>

#define N_NODES 100000
#define N_EDGES 1200000
#define D_IN 256
#define D_OUT 64
#define N_TILES (N_NODES / 16)                     // 6250 row tiles of 16

#define NG 1280                                    // GEMM blocks = 5/CU x 256
#define FUSED_NB (NG * 2)                          // even: GEMM, odd: edge
#define EDGE4_NB ((N_EDGES / 4 + 255) / 256)       // 1172 (4 edges/thread)

#define FILL_PASSES 2
#define PASS_NODES (N_NODES / FILL_PASSES)         // 50000
#define FILL_NB ((N_EDGES / 4 + 255) / 256)        // 1172

#define SCAN_BLOCK 1024
#define SCAN_NB ((N_NODES + SCAN_BLOCK - 1) / SCAN_BLOCK) // 98

typedef __bf16 bf16_t;
typedef bf16_t bf16x8 __attribute__((ext_vector_type(8)));
typedef float f32x4 __attribute__((ext_vector_type(4)));

// pack (col, val) into 4B: col<<15 | round(val*32767). val in [0,1).
__device__ __forceinline__ unsigned pack_cv(int col, float val) {
    return ((unsigned)col << 15) | (unsigned)(val * 32767.f + 0.5f);
}

__device__ __forceinline__ bf16x8 cvt8(float4 lo, float4 hi) {
    bf16x8 a;
    a[0] = (bf16_t)lo.x; a[1] = (bf16_t)lo.y;
    a[2] = (bf16_t)lo.z; a[3] = (bf16_t)lo.w;
    a[4] = (bf16_t)hi.x; a[5] = (bf16_t)hi.y;
    a[6] = (bf16_t)hi.z; a[7] = (bf16_t)hi.w;
    return a;
}

// async global->LDS, 16B per lane, dest = wave-uniform base + lane*16
__device__ __forceinline__ void gld_lds16(const void* g, void* l) {
    __builtin_amdgcn_global_load_lds(
        (const __attribute__((address_space(1))) void*)g,
        (__attribute__((address_space(3))) void*)l, 16, 0, 0);
}

// ---------------------------------------------------------------------------
// Kernel 1: pack W[256][64] (fp32) into MFMA B-fragment order, bf16.
// ---------------------------------------------------------------------------
__global__ __launch_bounds__(256) void pack_w(const float* __restrict__ W,
                                              bf16_t* __restrict__ Wpack) {
    int id = blockIdx.x * 256 + threadIdx.x;
    if (id < D_IN * D_OUT) {
        int i  = id & 7;
        int l  = (id >> 3) & 63;
        int n  = (id >> 9) & 3;
        int kk = id >> 11;
        int k = kk * 32 + (l >> 4) * 8 + i;
        int c = n * 16 + (l & 15);
        Wpack[id] = (bf16_t)W[k * D_OUT + c];
    }
}

// Stage one x tile (16 rows x 256 f32 = 16KB) into LDS, [kk][half][lane]x16B
// layout; per-lane-permuted global src, linear LDS dest (wave base + lane*16).
__device__ __forceinline__ void stage_tile(const char* __restrict__ xtile,
                                           char* ldsbuf, int wave, int lane) {
#pragma unroll
    for (int i = 0; i < 4; ++i) {
        int kk = i * 2 + (wave >> 1);
        const char* src = xtile + (lane & 15) * 1024 + (lane >> 4) * 32
                        + kk * 128 + (wave & 1) * 16;
        gld_lds16(src, ldsbuf + i * 4096 + wave * 1024);
    }
}

// Compute one tile from LDS, store its 16x16 output sub-tile (cols wave*16..).
// Issues exactly 4 global stores per wave (counted in the vmcnt formula).
__device__ __forceinline__ void compute_store(const char* buf,
                                              const bf16x8* wf,
                                              int lane, int lrow, int g, int wave,
                                              bf16_t* __restrict__ support,
                                              int tile) {
    f32x4 acc = {0.f, 0.f, 0.f, 0.f};
#pragma unroll
    for (int kk = 0; kk < 8; ++kk) {
        float4 lo = *(const float4*)(buf + kk * 2048 + lane * 16);
        float4 hi = *(const float4*)(buf + kk * 2048 + 1024 + lane * 16);
        acc = __builtin_amdgcn_mfma_f32_16x16x32_bf16(cvt8(lo, hi), wf[kk],
                                                      acc, 0, 0, 0);
    }
    bf16_t* __restrict__ sp = support + (size_t)tile * 16 * D_OUT
                            + wave * 16 + lrow;
#pragma unroll
    for (int q = 0; q < 4; ++q)
        sp[(g * 4 + q) * D_OUT] = (bf16_t)acc[q];
}

// ---------------------------------------------------------------------------
// Kernel 2 (fused, role-split): even blocks = GEMM; odd = edge chunk.
// vmcnt accounting (in-issue-order FIFO; stores count too):
//   iter FIFO at wait point: [4L stage-t][4S stores-(t-1)][4L stage-(t+1)]
//   -> steady wait = vmcnt(8) (retire oldest 4 = stage-t ONLY; do NOT
//   drain the previous tile's stores -- the old vmcnt(4) did, stalling
//   every iteration on store-ack). First iter: [8L wf][4L t0][4L t1] ->
//   vmcnt(4). Last iter (no stage): [4L t][4S] -> vmcnt(4).
// ---------------------------------------------------------------------------
__global__ __launch_bounds__(256, 5) void gemm_hist_cv(
        const float* __restrict__ x, const bf16x8* __restrict__ Wpack,
        bf16_t* __restrict__ support,
        const int* __restrict__ erow, const int* __restrict__ ecol,
        const float* __restrict__ eval,
        int* __restrict__ counts, unsigned* __restrict__ rcv) {
    __shared__ char xlds[2][16384];                // 32 KB double buffer
    int bid  = blockIdx.x;
    int role = bid & 1;
    int idx  = bid >> 1;
    if (role == 0) {
        // ---------------- GEMM role ----------------
        int lane = threadIdx.x & 63;
        int wave = threadIdx.x >> 6;
        int lrow = lane & 15;
        int g    = lane >> 4;

        // W fragments FIRST (oldest in VMEM FIFO; retired by first vmcnt(4))
        bf16x8 wf[8];
#pragma unroll
        for (int kk = 0; kk < 8; ++kk)
            wf[kk] = Wpack[(kk * 4 + wave) * 64 + lane];

        const char* xc = (const char*)x;
        int t = idx;                               // idx in [0, NG)
        stage_tile(xc + (size_t)t * 16384, xlds[0], wave, lane);

        int cur = 0;
#pragma unroll 1
        for (; t < N_TILES; t += NG) {
            int nxt = t + NG;
            if (nxt < N_TILES) {
                stage_tile(xc + (size_t)nxt * 16384, xlds[cur ^ 1], wave, lane);
                if (t == idx) {
                    asm volatile("s_waitcnt vmcnt(4)" ::: "memory");
                } else {
                    asm volatile("s_waitcnt vmcnt(8)" ::: "memory");
                }
            } else {
                asm volatile("s_waitcnt vmcnt(4)" ::: "memory");
            }
            __builtin_amdgcn_s_barrier();          // staged data visible
            __builtin_amdgcn_sched_barrier(0);     // pin ds_reads below
            compute_store(xlds[cur], wf, lane, lrow, g, wave, support, t);
            __builtin_amdgcn_s_barrier();          // all waves done reading
            __builtin_amdgcn_sched_barrier(0);     // pin next stage below
            cur ^= 1;
        }
    } else {
        // ---- edge role: histogram + pos capture + rcv pack ----
        if (idx >= EDGE4_NB) return;
        int e = (idx * 256 + threadIdx.x) * 4;
        if (e + 3 < N_EDGES) {
            int4   r4 = *(const int4*)(erow + e);
            int4   c4 = *(const int4*)(ecol + e);
            float4 v4 = *(const float4*)(eval + e);
            unsigned p0 = (unsigned)atomicAdd(&counts[r4.x], 1);
            unsigned p1 = (unsigned)atomicAdd(&counts[r4.y], 1);
            unsigned p2 = (unsigned)atomicAdd(&counts[r4.z], 1);
            unsigned p3 = (unsigned)atomicAdd(&counts[r4.w], 1);
            uint4 o1, o2;
            o1.x = pack_cv(c4.x, v4.x); o1.y = (unsigned)r4.x | (p0 << 17);
            o1.z = pack_cv(c4.y, v4.y); o1.w = (unsigned)r4.y | (p1 << 17);
            o2.x = pack_cv(c4.z, v4.z); o2.y = (unsigned)r4.z | (p2 << 17);
            o2.z = pack_cv(c4.w, v4.w); o2.w = (unsigned)r4.w | (p3 << 17);
            *(uint4*)(rcv + 2 * e)     = o1;
            *(uint4*)(rcv + 2 * e + 4) = o2;
        } else {
            for (int i = 0; i < 4; ++i) {
                if (e + i < N_EDGES) {
                    int rr = erow[e + i];
                    unsigned pp = (unsigned)atomicAdd(&counts[rr], 1);
                    rcv[2 * (e + i)]     = pack_cv(ecol[e + i], eval[e + i]);
                    rcv[2 * (e + i) + 1] = (unsigned)rr | (pp << 17);
                }
            }
        }
    }
}

// ---------------------------------------------------------------------------
// Kernel 3a: per-block partial sums of ceil4(counts) (quad-aligned segments).
// ---------------------------------------------------------------------------
__global__ __launch_bounds__(256) void partial_k(const int* __restrict__ counts,
                                                 int* __restrict__ bsum) {
    int b = blockIdx.x, t = threadIdx.x;
    int base = b * SCAN_BLOCK + t * 4;
    int s = 0;
    if (base + 3 < N_NODES) {
        int4 v = *(const int4*)(counts + base);
        s = ((v.x + 3) & ~3) + ((v.y + 3) & ~3) + ((v.z + 3) & ~3) + ((v.w + 3) & ~3);
    } else {
#pragma unroll
        for (int i = 0; i < 4; ++i)
            if (base + i < N_NODES) s += (counts[base + i] + 3) & ~3;
    }
#pragma unroll
    for (int off = 32; off > 0; off >>= 1) s += __shfl_down(s, off);
    __shared__ int sh[4];
    if ((t & 63) == 0) sh[t >> 6] = s;
    __syncthreads();
    if (t == 0) bsum[b] = sh[0] + sh[1] + sh[2] + sh[3];
}

// ---------------------------------------------------------------------------
// Kernel 3b: emit (merged with bsum scan): each block locally scans the 98
// block sums in LDS (tiny), then block-local scan of ceil4 degrees ->
// offsets. One launch fewer than the 3-kernel version.
// ---------------------------------------------------------------------------
__global__ __launch_bounds__(256) void emit_k(const int* __restrict__ counts,
                                              const int* __restrict__ bsum,
                                              int* __restrict__ offsets) {
    __shared__ int sb[128];
    __shared__ int sh[256];
    int b = blockIdx.x, t = threadIdx.x;
    if (t < 128) sb[t] = (t < SCAN_NB) ? bsum[t] : 0;
    __syncthreads();
    for (int off = 1; off < 128; off <<= 1) {
        int add = (t < 128 && t >= off) ? sb[t - off] : 0;
        __syncthreads();
        if (t < 128) sb[t] += add;
        __syncthreads();
    }
    int bpre = (b == 0) ? 0 : sb[b - 1];

    int base = b * SCAN_BLOCK + t * 4;
    int c0 = 0, c1 = 0, c2 = 0, c3 = 0;
    if (base + 3 < N_NODES) {
        int4 v = *(const int4*)(counts + base);
        c0 = (v.x + 3) & ~3; c1 = (v.y + 3) & ~3;
        c2 = (v.z + 3) & ~3; c3 = (v.w + 3) & ~3;
    } else {
        if (base + 0 < N_NODES) c0 = (counts[base + 0] + 3) & ~3;
        if (base + 1 < N_NODES) c1 = (counts[base + 1] + 3) & ~3;
        if (base + 2 < N_NODES) c2 = (counts[base + 2] + 3) & ~3;
        if (base + 3 < N_NODES) c3 = (counts[base + 3] + 3) & ~3;
    }
    int sum4 = c0 + c1 + c2 + c3;
    sh[t] = sum4;
    __syncthreads();
    for (int off = 1; off < 256; off <<= 1) {
        int add = (t >= off) ? sh[t - off] : 0;
        __syncthreads();
        sh[t] += add;
        __syncthreads();
    }
    int run = bpre + sh[t] - sum4;
    if (base + 0 < N_NODES) { offsets[base + 0] = run; run += c0; }
    if (base + 1 < N_NODES) { offsets[base + 1] = run; run += c1; }
    if (base + 2 < N_NODES) { offsets[base + 2] = run; run += c2; }
    if (base + 3 < N_NODES) { offsets[base + 3] = run; run += c3; }
}

// ---------------------------------------------------------------------------
// Kernel 4: atomic-free predicated CSR fill: dst = offsets[row] + pos.
// ---------------------------------------------------------------------------
__global__ __launch_bounds__(256) void fill_k(const unsigned* __restrict__ rcv,
                                              const int* __restrict__ offsets,
                                              unsigned* __restrict__ csr,
                                              int lo, int hi) {
    int t = blockIdx.x * 256 + threadIdx.x;
    int e = t * 4;
    if (e + 3 < N_EDGES) {
        uint4 A = *(const uint4*)(rcv + 2 * e);
        uint4 B = *(const uint4*)(rcv + 2 * e + 4);
        int r0 = (int)(A.y & 0x1ffffu), p0 = (int)(A.y >> 17);
        int r1 = (int)(A.w & 0x1ffffu), p1 = (int)(A.w >> 17);
        int r2 = (int)(B.y & 0x1ffffu), p2 = (int)(B.y >> 17);
        int r3 = (int)(B.w & 0x1ffffu), p3 = (int)(B.w >> 17);
        int o0 = offsets[r0];
        int o1 = offsets[r1];
        int o2 = offsets[r2];
        int o3 = offsets[r3];
        if (r0 >= lo && r0 < hi) csr[o0 + p0] = A.x;
        if (r1 >= lo && r1 < hi) csr[o1 + p1] = A.z;
        if (r2 >= lo && r2 < hi) csr[o2 + p2] = B.x;
        if (r3 >= lo && r3 < hi) csr[o3 + p3] = B.z;
    } else {
        for (int i = 0; i < 4; ++i) {
            if (e + i < N_EDGES) {
                unsigned cw = rcv[2 * (e + i)];
                unsigned rw = rcv[2 * (e + i) + 1];
                int rr = (int)(rw & 0x1ffffu);
                int pp = (int)(rw >> 17);
                if (rr >= lo && rr < hi) csr[offsets[rr] + pp] = cw;
            }
        }
    }
}

// ---------------------------------------------------------------------------
// Kernel 5: aggregate + ReLU. 4 nodes/wave: quarter-wave (16 lanes) per
// node, lane = uint2 (4 bf16 features, 8B) -> still 128B/edge gather but
// 4 independent node streams x 8-deep = 32 outstanding gathers/wave.
// ---------------------------------------------------------------------------
__global__ __launch_bounds__(256) void agg_k(const int* __restrict__ offsets,
                                             const int* __restrict__ counts,
                                             const unsigned* __restrict__ csr,
                                             const uint2* __restrict__ supq,
                                             float* __restrict__ out) {
    int wave = threadIdx.x >> 6;
    int lane = threadIdx.x & 63;
    int q4   = lane >> 4;
    int fl   = lane & 15;
    int node = blockIdx.x * 16 + wave * 4 + q4;
    if (node >= N_NODES) return;
    int s = offsets[node];
    int e = s + counts[node];
    const float inv = 1.f / 32767.f;
    float a0 = 0.f, a1 = 0.f, a2 = 0.f, a3 = 0.f;
    int p = s;
#define ACC(w, qq) { float v = (float)((w) & 0x7fffu) * inv;                    \
        a0 = fmaf(v, __uint_as_float((qq).x << 16), a0);                        \
        a1 = fmaf(v, __uint_as_float((qq).x & 0xffff0000u), a1);                \
        a2 = fmaf(v, __uint_as_float((qq).y << 16), a2);                        \
        a3 = fmaf(v, __uint_as_float((qq).y & 0xffff0000u), a3); }
    for (; p + 8 <= e; p += 8) {
        uint4 A = *(const uint4*)(csr + p);
        uint4 B = *(const uint4*)(csr + p + 4);
        uint2 q0 = supq[(size_t)(A.x >> 15) * 16 + fl];
        uint2 q1 = supq[(size_t)(A.y >> 15) * 16 + fl];
        uint2 q2 = supq[(size_t)(A.z >> 15) * 16 + fl];
        uint2 q3 = supq[(size_t)(A.w >> 15) * 16 + fl];
        uint2 q4v = supq[(size_t)(B.x >> 15) * 16 + fl];
        uint2 q5 = supq[(size_t)(B.y >> 15) * 16 + fl];
        uint2 q6 = supq[(size_t)(B.z >> 15) * 16 + fl];
        uint2 q7 = supq[(size_t)(B.w >> 15) * 16 + fl];
        ACC(A.x, q0) ACC(A.y, q1) ACC(A.z, q2) ACC(A.w, q3)
        ACC(B.x, q4v) ACC(B.y, q5) ACC(B.z, q6) ACC(B.w, q7)
    }
    if (p + 4 <= e) {
        uint4 A = *(const uint4*)(csr + p);
        uint2 q0 = supq[(size_t)(A.x >> 15) * 16 + fl];
        uint2 q1 = supq[(size_t)(A.y >> 15) * 16 + fl];
        uint2 q2 = supq[(size_t)(A.z >> 15) * 16 + fl];
        uint2 q3 = supq[(size_t)(A.w >> 15) * 16 + fl];
        ACC(A.x, q0) ACC(A.y, q1) ACC(A.z, q2) ACC(A.w, q3)
        p += 4;
    }
    for (; p < e; ++p) {
        unsigned w = csr[p];
        uint2 q = supq[(size_t)(w >> 15) * 16 + fl];
        ACC(w, q)
    }
#undef ACC
    float4 r;
    r.x = fmaxf(a0, 0.f);
    r.y = fmaxf(a1, 0.f);
    r.z = fmaxf(a2, 0.f);
    r.w = fmaxf(a3, 0.f);
    *(float4*)(out + (size_t)node * D_OUT + fl * 4) = r;
}

extern "C" void kernel_launch(void* const* d_in, const int* in_sizes, int n_in,
                              void* d_out, int out_size, void* d_ws, size_t ws_size,
                              hipStream_t stream) {
    const float* x    = (const float*)d_in[0];
    const int*   erow = (const int*)d_in[1];
    const int*   ecol = (const int*)d_in[2];
    const float* eval = (const float*)d_in[3];
    const float* W    = (const float*)d_in[4];
    float* out = (float*)d_out;

    // ---- workspace layout (16B-aligned segments, ~29.3 MB) ----
    char* ws = (char*)d_ws;
    bf16_t*   support = (bf16_t*)ws;                         // 12,800,000
    bf16_t*   WpackS  = (bf16_t*)(ws + 12800000);            //     32,768
    int*      counts  = (int*)(ws + 12832768);               //    400,000
    int*      offsets = (int*)(ws + 13232768);               //    400,016
    unsigned* rcv     = (unsigned*)(ws + 13632784);          //  9,600,000
    unsigned* csr     = (unsigned*)(ws + 23232784);          //  6,000,000 (padded)
    int*      bsum    = (int*)(ws + 29232784);               //        392

    // 1) pack W into bf16 MFMA B-fragments
    pack_w<<<(D_IN * D_OUT + 255) / 256, 256, 0, stream>>>(W, WpackS);

    // 2) zero counts, then fused role-split GEMM + edge (hist + pos + rcv)
    hipMemsetAsync(counts, 0, (size_t)N_NODES * sizeof(int), stream);
    gemm_hist_cv<<<FUSED_NB, 256, 0, stream>>>(
        x, (const bf16x8*)WpackS, support, erow, ecol, eval, counts, rcv);

    // 3) scan (2 launches: partial sums, then merged bsum-scan + emit)
    partial_k<<<SCAN_NB, 256, 0, stream>>>(counts, bsum);
    emit_k<<<SCAN_NB, 256, 0, stream>>>(counts, bsum, offsets);

    // 4) atomic-free predicated CSR fill, 2 L2-localized passes
    for (int p = 0; p < FILL_PASSES; ++p) {
        fill_k<<<FILL_NB, 256, 0, stream>>>(rcv, offsets, csr,
                                            p * PASS_NODES, (p + 1) * PASS_NODES);
    }

    // 5) aggregate + ReLU (no atomics, writes every output element)
    agg_k<<<(N_NODES + 15) / 16, 256, 0, stream>>>(offsets, counts, csr,
                                                   (const uint2*)support, out);
}